// Round 9
// baseline (2112.936 us; speedup 1.0000x reference)
//
#include <hip/hip_runtime.h>
#include <hip/hip_bf16.h>
#include <math.h>

typedef __hip_bfloat16 bf16;

#define NPTS  8192
#define BATCH 2
#define KNB   16
#define NPART 16
#define PARTC (NPTS / NPART)   // 512
#define CAP   24               // knn pass-2 capture buffer per thread
#define BN    (BATCH * NPTS)

#define C_IE 0.9999950000374997f   // 1/sqrt(1+1e-5)
#define C_PM 0.9995003746877732f   // 1/sqrt(1+1e-3)

// ---- weight block float offsets inside ws ----
enum {
  WOFF_CW1A = 0,     WOFF_CB1A = 8192,  WOFF_CW1B = 8256,  WOFF_CB1B = 12352,
  WOFF_CW2A = 12416, WOFF_CB2A = 20608, WOFF_CW2B = 20672, WOFF_CB2B = 24768,
  WOFF_CW3A = 24832, WOFF_CB3A = 29120, WOFF_CW3B = 29184, WOFF_CB3B = 33280,
  WOFF_CW4A = 33344, WOFF_CB4A = 41536, WOFF_CW4B = 41600, WOFF_CB4B = 45696,
  WOFF_IEW1 = 45760, WOFF_IEB1 = 45952, WOFF_IEG  = 46016, WOFF_IEBT = 46080,
  WOFF_IEW2 = 46144, WOFF_IEB2 = 50240, WOFF_PECW = 50304, WOFF_PECB = 51840,
  WOFF_PMW1 = 51904, WOFF_PMB1 = 56000, WOFF_PMG1 = 56064, WOFF_PMT1 = 56128,
  WOFF_PMW2 = 56192, WOFF_PMB2 = 60288, WOFF_PMG2 = 60352, WOFF_PMT2 = 60416,
  WOFF_PMW3 = 60480, WOFF_PMB3 = 62528, WOFF_PMG3 = 62560, WOFF_PMT3 = 62592,
  WOFF_PMW4 = 62624, WOFF_PMB4 = 62656, WOFF_PMG4 = 62657, WOFF_PMT4 = 62658
};

// ---- ws byte offsets (unchanged known-good footprint; AW slot now unused) ----
#define BOFF_W    0u
#define BOFF_FLAG 262144u
#define BOFF_PK   262160u     // 4 x [B*N] float4 (1 MB)
#define BOFF_WB   1310736u    // MFMA weight frags: 124 x 64 lanes x 32 B = 248 KB
#define BOFF_IDX  2359312u    // final idx [2][B][N][16] i32 (2 MB)
#define BOFF_AW   4456464u    // (unused after logit/feat fusion)
#define BOFF_P1T  5505040u    // points1^T packed hi|lo u32 [B][N][64] (4 MB)
#define BOFF_P2T  9699344u    // points2^T packed hi|lo u32 [B][N][64] (4 MB)
#define BOFF_PART BOFF_P1T    // knn partials aliased over P1T/P2T+slack; k_tr after k_merge

typedef __attribute__((ext_vector_type(4))) float f32x4;
typedef __attribute__((ext_vector_type(8))) short bf16x8;
typedef __attribute__((ext_vector_type(4))) unsigned int u32x4;

__device__ __forceinline__ float lrelu(float v) { return v > 0.f ? v : 0.1f * v; }

__device__ __forceinline__ float ldin(const void* p, size_t i, int f32) {
  return f32 ? ((const float*)p)[i] : __bfloat162float(((const bf16*)p)[i]);
}
__device__ __forceinline__ void stout(void* p, size_t i, float v, int f32) {
  if (f32) ((float*)p)[i] = v;
  else ((bf16*)p)[i] = __float2bfloat16(v);
}

// bf16 round-nearest-even split: x ~= hi + lo (hi,lo bf16 bit patterns)
__device__ __forceinline__ unsigned int bf16rne(float x) {
  unsigned int u = __float_as_uint(x);
  return (u + 0x7fffu + ((u >> 16) & 1u)) >> 16;
}
__device__ __forceinline__ void splitbf(float x, unsigned int& h, unsigned int& l) {
  h = bf16rne(x);
  float hf = __uint_as_float(h << 16);
  l = bf16rne(x - hf);
}
__device__ __forceinline__ unsigned int packbf(float v) {
  unsigned int h, lo;
  splitbf(v, h, lo);
  return h | (lo << 16);
}

// stable top-16 insertion (keeps lower index on ties when fed ascending j)
__device__ __forceinline__ void insert16(float d, int id, float* best, int* bidx) {
#pragma unroll
  for (int p = 0; p < KNB; ++p) {
    bool c = d < best[p];
    float tb = best[p]; int ti = bidx[p];
    best[p] = c ? d : tb; bidx[p] = c ? id : ti;
    d = c ? tb : d; id = c ? ti : id;
  }
}

// one bitonic compare-exchange pass over a 16-float register array.
// J,K are literal constants -> indices fold to constants, array stays in regs.
#define BPASS(arr, J, K) \
  _Pragma("unroll") \
  for (int i = 0; i < 16; ++i) { \
    int ix = i ^ (J); \
    if (ix > i) { \
      float lo = fminf(arr[i], arr[ix]); \
      float hi = fmaxf(arr[i], arr[ix]); \
      if ((i & (K)) == 0) { arr[i] = lo; arr[ix] = hi; } \
      else { arr[i] = hi; arr[ix] = lo; } \
    } \
  }

// exact reference distance chain (bit-replicates f32 expanded form)
__device__ __forceinline__ float qsq(float4 qv) {
  return __fadd_rn(__fadd_rn(__fmul_rn(qv.x, qv.x), __fmul_rn(qv.y, qv.y)),
                   __fmul_rn(qv.z, qv.z));
}
__device__ __forceinline__ float refdist(float4 qv, float sq, float4 rv) {
  float sr = qsq(rv);
  float dot = __fmaf_rn(qv.z, rv.z, __fmaf_rn(qv.y, rv.y, __fmul_rn(qv.x, rv.x)));
  return __fsub_rn(__fadd_rn(sq, sr), __fadd_rn(dot, dot));
}
__device__ __forceinline__ float refdist_sr(float4 qv, float sq, float4 rv) {
  float dot = __fmaf_rn(qv.z, rv.z, __fmaf_rn(qv.y, rv.y, __fmul_rn(qv.x, rv.x)));
  return __fsub_rn(__fadd_rn(sq, rv.w), __fadd_rn(dot, dot));
}

// ---------------- dtype autodetect ----------------
__global__ void k_detect(const void* __restrict__ pts1, int* __restrict__ flag) {
  int tid = threadIdx.x;  // 64
  const bf16* p = (const bf16*)pts1;
  int cnt = 0;
  for (int i = tid; i < 1024; i += 64) {
    float v = __bfloat162float(p[i]);
    if (!(fabsf(v) <= 64.f)) cnt++;
  }
#pragma unroll
  for (int s = 32; s; s >>= 1) cnt += __shfl_down(cnt, s);
  if (tid == 0) *flag = (cnt >= 8) ? 1 : 0;
}

// ---------------- prep ----------------
struct PrepTab {
  const void* src[40];
  int off[40];
  int n[40];
  float scale[40];
};

__global__ void k_prep(PrepTab tab, float* __restrict__ W, const int* __restrict__ flag) {
  int f32 = *flag;
  int a = blockIdx.x;
  const void* s = tab.src[a];
  float* d = W + tab.off[a];
  float sc = tab.scale[a];
  for (int i = threadIdx.x; i < tab.n[a]; i += blockDim.x) d[i] = ldin(s, i, f32) * sc;
}

// ---------------- MFMA weight fragment prep ----------------
// frag f: 64 lanes x {hi float4(8 bf16), lo float4}. B-layout: lane l holds
// W[srck(ks*32+(l>>4)*8+e)][nt*16+(l&15)], word r = elem2r | elem2r+1<<16.
// mode 0: srck = k (<kreal else 0). mode 1 (cw3a): A=[f2(64)|pd(3)|0]:
//   k<64 -> k+3; 64..66 -> k-64; else 0.
struct WTab { int woff[16]; int nn[16]; int kreal[16]; int mode[16]; int fb[16]; int nm; };

__global__ __launch_bounds__(64) void k_wbprep(WTab wt, const float* __restrict__ W,
                                               unsigned int* __restrict__ WB) {
  int f = blockIdx.x, l = threadIdx.x;
  int m = 0;
  for (int i = 1; i < wt.nm; ++i)
    if (wt.fb[i] <= f) m = i;
  int ntile = wt.nn[m] >> 4;
  int local = f - wt.fb[m];
  int ks = local / ntile, nt = local - ks * ntile;
  int g = l >> 4, c = l & 15;
  int col = nt * 16 + c;
  int N = wt.nn[m], kr = wt.kreal[m], wo = wt.woff[m], mode = wt.mode[m];
  unsigned int hw[4], lw[4];
#pragma unroll
  for (int r = 0; r < 4; ++r) {
    float wv2[2];
#pragma unroll
    for (int e = 0; e < 2; ++e) {
      int k = ks * 32 + g * 8 + 2 * r + e;
      int srck;
      if (mode == 1) srck = (k < 64) ? k + 3 : ((k < 67) ? k - 64 : -1);
      else srck = (k < kr) ? k : -1;
      wv2[e] = (srck >= 0) ? W[wo + srck * N + col] : 0.f;
    }
    unsigned int h0, l0, h1, l1;
    splitbf(wv2[0], h0, l0);
    splitbf(wv2[1], h1, l1);
    hw[r] = h0 | (h1 << 16);
    lw[r] = l0 | (l1 << 16);
  }
  unsigned int* d = WB + ((size_t)f * 64 + l) * 8;
  d[0] = hw[0]; d[1] = hw[1]; d[2] = hw[2]; d[3] = hw[3];
  d[4] = lw[0]; d[5] = lw[1]; d[6] = lw[2]; d[7] = lw[3];
}

// ---------------- pack (w = qsq, bit-identical chain to the old tile staging) --
__global__ void k_pack(const void* __restrict__ xyz1, const void* __restrict__ xyz2,
                       const void* __restrict__ xyz2w, const void* __restrict__ sf,
                       float4* __restrict__ pk, const int* __restrict__ flag) {
  int f32 = *flag;
  int t = blockIdx.x * 256 + threadIdx.x;  // B*N
  int b = t >> 13, n = t & (NPTS - 1);
  size_t base = (size_t)b * 3 * NPTS + n;
  float ax = ldin(xyz1, base, f32), ay = ldin(xyz1, base + NPTS, f32), az = ldin(xyz1, base + 2 * NPTS, f32);
  float sx = ldin(sf, base, f32),   sy = ldin(sf, base + NPTS, f32),   sz = ldin(sf, base + 2 * NPTS, f32);
  float4 p0 = make_float4(__fadd_rn(ax, sx), __fadd_rn(ay, sy), __fadd_rn(az, sz), 0.f);
  p0.w = qsq(p0);
  float4 p1 = make_float4(ax, ay, az, 0.f);
  p1.w = qsq(p1);
  float4 p2 = make_float4(ldin(xyz2, base, f32), ldin(xyz2, base + NPTS, f32), ldin(xyz2, base + 2 * NPTS, f32), 0.f);
  p2.w = qsq(p2);
  float4 p3 = make_float4(ldin(xyz2w, base, f32), ldin(xyz2w, base + NPTS, f32), ldin(xyz2w, base + 2 * NPTS, f32), 0.f);
  p3.w = qsq(p3);
  pk[t]          = p0;
  pk[t + BN]     = p1;
  pk[t + 2 * BN] = p2;
  pk[t + 3 * BN] = p3;
}

// ---------------- transpose (writes packed hi|lo u32) ----------------
__global__ __launch_bounds__(64) void k_tr(const void* __restrict__ src,
                                           unsigned int* __restrict__ dst,
                                           const int* __restrict__ flag) {
  __shared__ float tile[64][65];
  int f32 = *flag;
  int tid = threadIdx.x;
  int n0 = blockIdx.x * 64;
  int b = blockIdx.y;
  for (int i = 0; i < 64; ++i)
    tile[i][tid] = ldin(src, ((size_t)b * 64 + i) * NPTS + n0 + tid, f32);
  __syncthreads();
  for (int i = 0; i < 64; ++i)
    dst[((size_t)b * NPTS + n0 + i) * 64 + tid] = packbf(tile[tid][i]);
}

// ---------------- KNN partials: scalar-broadcast ref reads (no LDS tile) -----
__global__ __launch_bounds__(256) void k_knnp(const float4* __restrict__ pk,
                                              unsigned short* __restrict__ part_idx) {
  __shared__ unsigned short sbuf[256 * CAP];
  int tid = threadIdx.x;
  int n = blockIdx.x * 256 + tid;
  int b = blockIdx.y;
  int which = blockIdx.z >> 4;   // NPART==16
  int part  = blockIdx.z & 15;
  const float4* q = pk + (size_t)which * BN;
  const float4* r = pk + (size_t)(2 + which) * BN + (size_t)b * NPTS;
  float4 qv = q[b * NPTS + n];
  float sq = qsq(qv);

  float best[KNB];
#pragma unroll
  for (int p = 0; p < KNB; ++p) best[p] = 3.4e38f;   // sorted asc (all equal)

  const int c0 = part * PARTC;
  // pass 1: exact 16 smallest distance VALUES (batched bitonic)
  for (int t = 0; t < PARTC / 16; ++t) {
    const float4* rr = r + c0 + t * 16;   // uniform across the wave
    float fr[16];
#pragma unroll
    for (int j = 0; j < 16; ++j) fr[j] = refdist_sr(qv, sq, rr[j]);
    // bitonic sort fr ascending (10 passes)
    BPASS(fr, 1, 2)
    BPASS(fr, 2, 4) BPASS(fr, 1, 4)
    BPASS(fr, 4, 8) BPASS(fr, 2, 8) BPASS(fr, 1, 8)
    BPASS(fr, 8, 16) BPASS(fr, 4, 16) BPASS(fr, 2, 16) BPASS(fr, 1, 16)
    // min-merge: keep 16 smallest of best(asc) U fr(asc) -> bitonic in best
#pragma unroll
    for (int i = 0; i < 16; ++i) best[i] = fminf(best[i], fr[15 - i]);
    // bitonic cleanup -> best sorted asc again (K=16: all-ascending passes)
    BPASS(best, 8, 16) BPASS(best, 4, 16) BPASS(best, 2, 16) BPASS(best, 1, 16)
  }
  float thr = best[KNB - 1];

  // pass 2: capture candidate indices with dd <= thr (ascending global index)
  int cnt = 0;
  for (int t = 0; t < PARTC / 16; ++t) {
    const float4* rr = r + c0 + t * 16;   // uniform across the wave
#pragma unroll
    for (int j = 0; j < 16; ++j) {
      float dd = refdist_sr(qv, sq, rr[j]);
      if (dd <= thr && cnt < CAP) {
        sbuf[tid * CAP + cnt] = (unsigned short)(c0 + t * 16 + j);
        cnt++;
      }
    }
  }

  // post: exact (d, idx) selection among <=CAP captured
  float bd[KNB]; int bi[KNB];
#pragma unroll
  for (int p = 0; p < KNB; ++p) { bd[p] = 3.4e38f; bi[p] = 0; }
  for (int m = 0; m < CAP; ++m) {
    if (m < cnt) {
      int id = sbuf[tid * CAP + m];
      float dd = refdist(qv, sq, r[id]);
      insert16(dd, id, bd, bi);
    }
  }
  size_t o = ((((size_t)which * BATCH + b) * NPART + part) * NPTS + n) * KNB;
#pragma unroll
  for (int p = 0; p < KNB; ++p) part_idx[o + p] = (unsigned short)bi[p];
}

// ---------------- KNN merge (16 parts x 16 u16 candidates, ascending feed) ----
__global__ void k_merge(const float4* __restrict__ pk,
                        const unsigned short* __restrict__ part_idx,
                        int* __restrict__ idxf) {
  int t = blockIdx.x * 256 + threadIdx.x;  // (which*B+b)*N+n
  int n = t & (NPTS - 1);
  int wb = t >> 13;
  int b = wb & (BATCH - 1);
  int which = wb / BATCH;
  const float4* q = pk + (size_t)which * BN;
  const float4* r = pk + (size_t)(2 + which) * BN + (size_t)b * NPTS;
  float4 qv = q[b * NPTS + n];
  float sq = qsq(qv);
  float best[KNB]; int bidx[KNB];
#pragma unroll
  for (int p = 0; p < KNB; ++p) { best[p] = 3.4e38f; bidx[p] = 0; }
  for (int part = 0; part < NPART; ++part) {
    size_t o = ((((size_t)which * BATCH + b) * NPART + part) * NPTS + n) * KNB;
#pragma unroll
    for (int m = 0; m < KNB; ++m) {
      int id = part_idx[o + m];
      float dd = refdist(qv, sq, r[id]);
      if (dd < best[KNB - 1]) insert16(dd, id, best, bidx);
    }
  }
  size_t oo = (size_t)t * KNB;
#pragma unroll
  for (int p = 0; p < KNB; ++p) idxf[oo + p] = bidx[p];
}

// ---------------- MFMA helpers ----------------
__device__ __forceinline__ bf16x8 mk8(unsigned int w0, unsigned int w1,
                                      unsigned int w2, unsigned int w3) {
  u32x4 u;
  u.x = w0; u.y = w1; u.z = w2; u.w = w3;
  return __builtin_bit_cast(bf16x8, u);
}

// build A hi/lo frags from 8 packed (hi|lo<<16) u32
__device__ __forceinline__ void mkA_pk(u32x4 qa, u32x4 qb, bf16x8& ah, bf16x8& al) {
  unsigned int q0 = qa.x, q1 = qa.y, q2 = qa.z, q3 = qa.w;
  unsigned int q4 = qb.x, q5 = qb.y, q6 = qb.z, q7 = qb.w;
  ah = mk8((q0 & 0xffffu) | (q1 << 16), (q2 & 0xffffu) | (q3 << 16),
           (q4 & 0xffffu) | (q5 << 16), (q6 & 0xffffu) | (q7 << 16));
  al = mk8((q0 >> 16) | (q1 & 0xffff0000u), (q2 >> 16) | (q3 & 0xffff0000u),
           (q4 >> 16) | (q5 & 0xffff0000u), (q6 >> 16) | (q7 & 0xffff0000u));
}
__device__ __forceinline__ void mkA_lds(const unsigned int* p, bf16x8& ah, bf16x8& al) {
  mkA_pk(*(const u32x4*)p, *(const u32x4*)(p + 4), ah, al);
}

#define FRAG_IEW2 0
#define FRAG_PECW 8
#define FRAG_PMW1 12
#define FRAG_PMW2 20
#define FRAG_PMW3 28
#define FRAG_C1A  32
#define FRAG_C1B  48
#define FRAG_C2A  56
#define FRAG_C2B  72
#define FRAG_C3A  80
#define FRAG_C3B  92
#define FRAG_C4A  100
#define FRAG_C4B  116
#define NFRAG     124

// acc += A * Wfrag with split-bf16 3-product emulation
__device__ __forceinline__ f32x4 mfma_bb(bf16x8 ah, bf16x8 al,
                                         const unsigned int* __restrict__ WB,
                                         int f, int lane, f32x4 acc) {
  const u32x4* p = (const u32x4*)WB + ((size_t)(f * 64 + lane)) * 2;
  u32x4 h4 = p[0], l4 = p[1];
  bf16x8 bh = __builtin_bit_cast(bf16x8, h4);
  bf16x8 bl = __builtin_bit_cast(bf16x8, l4);
  acc = __builtin_amdgcn_mfma_f32_16x16x32_bf16(al, bh, acc, 0, 0, 0);
  acc = __builtin_amdgcn_mfma_f32_16x16x32_bf16(ah, bl, acc, 0, 0, 0);
  acc = __builtin_amdgcn_mfma_f32_16x16x32_bf16(ah, bh, acc, 0, 0, 0);
  return acc;
}

// one 64->64 layer: A from xp (sample row = lane&15), 2 k-steps x 4 n-tiles
__device__ __forceinline__ void layer64(const unsigned int* __restrict__ xp,
                                        const unsigned int* __restrict__ WB,
                                        int fbase, int lane, f32x4 acc[4]) {
  int c = lane & 15, g = lane >> 4;
  bf16x8 ah0, al0, ah1, al1;
  mkA_lds(xp + c * 68 + g * 8, ah0, al0);
  mkA_lds(xp + c * 68 + 32 + g * 8, ah1, al1);
#pragma unroll
  for (int nt = 0; nt < 4; ++nt) {
    acc[nt] = mfma_bb(ah0, al0, WB, fbase + nt, lane, acc[nt]);
    acc[nt] = mfma_bb(ah1, al1, WB, fbase + 4 + nt, lane, acc[nt]);
  }
}

// epilogue: optional bn(+relu), split to bf16 hi/lo, pack, write to xp
__device__ __forceinline__ void epi_pack(int lane, f32x4 acc[4], unsigned int* xp,
                                         const float* gw, const float* bw, bool relu) {
  int c = lane & 15, g = lane >> 4;
#pragma unroll
  for (int nt = 0; nt < 4; ++nt) {
    float gv = gw ? gw[nt * 16 + c] : 1.f;
    float bv = gw ? bw[nt * 16 + c] : 0.f;
#pragma unroll
    for (int r = 0; r < 4; ++r) {
      float v = acc[nt][r];
      if (gw) v = fmaf(v, gv, bv);
      if (relu) v = fmaxf(v, 0.f);
      xp[(g * 4 + r) * 68 + nt * 16 + c] = packbf(v);
    }
  }
}

// epilogue with leaky relu (k_feat chains)
__device__ __forceinline__ void epi_lrelu(int lane, f32x4 acc[4], unsigned int* xp) {
  int c = lane & 15, g = lane >> 4;
#pragma unroll
  for (int nt = 0; nt < 4; ++nt) {
#pragma unroll
    for (int r = 0; r < 4; ++r)
      xp[(g * 4 + r) * 68 + nt * 16 + c] = packbf(lrelu(acc[nt][r]));
  }
}

// ---------------- k_feat: fused IPC-logit + chains on matrix cores -----------
// block = 4 waves = 4 points; wave = one point's 16 neighbors (16-sample batch).
// Per which: IPC MLP (trig->ie1->ie2+pec->pm1..pm4->softmax) produces the
// attention weights IN-REGISTER (sample g*4+r in lane group g == exactly the
// a4r components the weighted-sum consumes), then the feature chains run on the
// same xp LDS buffer. Full-precision aw (u16 AW round-trip eliminated).
__global__ __launch_bounds__(256, 3) void k_feat(const unsigned int* __restrict__ P1T,
                                                 const unsigned int* __restrict__ P2T,
                                                 const float* __restrict__ W,
                                                 const unsigned int* __restrict__ WB,
                                                 const int* __restrict__ idxf,
                                                 const float4* __restrict__ pk,
                                                 void* __restrict__ out,
                                                 const int* __restrict__ flag) {
  __shared__ unsigned int xp_s[4][16 * 68];
  __shared__ unsigned int tg_s[4][16 * 36];  // packed trig rows (24 real + 8 zero)
  __shared__ unsigned int costb[4][132];     // [point][costA(64)|costB(64)] packed
  __shared__ unsigned int u4b[4][68];        // chain4 mid activations [point][64]
  const int l = threadIdx.x & 63;
  const int wv = threadIdx.x >> 6;
  const int c = l & 15, g = l >> 4;
  unsigned int* xp = xp_s[wv];
  unsigned int* tg = tg_s[wv];
  const int f32 = *flag;
  const int pt = blockIdx.x * 4 + wv;    // b*N+n
  const int n = pt & (NPTS - 1);
  const int b = pt >> 13;
  float4 qp = pk[(size_t)BN + pt];       // x1[n]
  u32x4 z4;
  z4.x = 0u; z4.y = 0u; z4.z = 0u; z4.w = 0u;

  // gp1 fragments (layer-a k-steps 0,1): row n broadcast
  bf16x8 p1h[2], p1l[2];
  {
    const unsigned int* pr = P1T + ((size_t)b * NPTS + n) * 64;
#pragma unroll
    for (int ks = 0; ks < 2; ++ks) {
      u32x4 qa = *(const u32x4*)(pr + ks * 32 + g * 8);
      u32x4 qb = *(const u32x4*)(pr + ks * 32 + g * 8 + 4);
      mkA_pk(qa, qb, p1h[ks], p1l[ks]);
    }
  }

  for (int which = 0; which < 2; ++which) {
    int idxv = idxf[(((size_t)which * BATCH + b) * NPTS + n) * KNB + c];
    float4 pv = pk[(size_t)2 * BN + (size_t)b * NPTS + idxv];  // x2[idx]
    float pdx = pv.x - qp.x, pdy = pv.y - qp.y, pdz = pv.z - qp.z;

    // ======== IPC logit MLP (was k_logit) ========
    // trig: 12 sincos per sample, 3 per k-group lane
    {
      unsigned int* tr = tg + c * 36;
#pragma unroll
      for (int j = 0; j < 3; ++j) {
        int t = g * 3 + j;
        int c3 = t >> 2, fq = t & 3;
        float pdc = (c3 == 0) ? pdx : (c3 == 1) ? pdy : pdz;
        float pe = (pdc - rintf(pdc * 4.f) * 0.25f) * 4.f;
        float tt = pe / 1.000001f * 6.28318530717958647692f;
        float dv = (fq == 0) ? 1.f : (fq == 1) ? 10.f : (fq == 2) ? 100.f : 1000.f;
        float sn, cs;
        sincosf(tt / dv, &sn, &cs);
        unsigned int hs, ls2, hc, lc;
        splitbf(sn, hs, ls2);
        splitbf(cs, hc, lc);
        tr[2 * t] = hs | (ls2 << 16);
        tr[2 * t + 1] = hc | (lc << 16);
      }
      if (g == 3) {
#pragma unroll
        for (int z = 24; z < 32; ++z) tr[z] = 0u;
      }
    }

    // ie1: 3->64, bn, relu (exact f32), pack to xp[sample=c][ch]
    {
      unsigned int* xr = xp + c * 68 + g * 16;
#pragma unroll
      for (int m4 = 0; m4 < 4; ++m4) {
        int ch = g * 16 + m4 * 4;
        float4 bb = *(const float4*)(W + WOFF_IEB1 + ch);
        float4 w0 = *(const float4*)(W + WOFF_IEW1 + ch);
        float4 w1 = *(const float4*)(W + WOFF_IEW1 + 64 + ch);
        float4 w2 = *(const float4*)(W + WOFF_IEW1 + 128 + ch);
        float4 gg = *(const float4*)(W + WOFF_IEG + ch);
        float4 bt = *(const float4*)(W + WOFF_IEBT + ch);
        float v0 = fmaf(pdz, w2.x, fmaf(pdy, w1.x, fmaf(pdx, w0.x, bb.x)));
        float v1 = fmaf(pdz, w2.y, fmaf(pdy, w1.y, fmaf(pdx, w0.y, bb.y)));
        float v2 = fmaf(pdz, w2.z, fmaf(pdy, w1.z, fmaf(pdx, w0.z, bb.z)));
        float v3 = fmaf(pdz, w2.w, fmaf(pdy, w1.w, fmaf(pdx, w0.w, bb.w)));
        v0 = fmaxf(fmaf(v0, gg.x, bt.x), 0.f);
        v1 = fmaxf(fmaf(v1, gg.y, bt.y), 0.f);
        v2 = fmaxf(fmaf(v2, gg.z, bt.z), 0.f);
        v3 = fmaxf(fmaf(v3, gg.w, bt.w), 0.f);
        u32x4 pk4;
        pk4.x = packbf(v0); pk4.y = packbf(v1);
        pk4.z = packbf(v2); pk4.w = packbf(v3);
        *(u32x4*)(xr + m4 * 4) = pk4;
      }
    }
    __builtin_amdgcn_wave_barrier();

    f32x4 acc[4];
    // ie2 + pec (accumulated into one f32 acc; init = ie_b2 + pec_b)
#pragma unroll
    for (int nt = 0; nt < 4; ++nt) {
      float bs = W[WOFF_IEB2 + nt * 16 + c] + W[WOFF_PECB + nt * 16 + c];
      acc[nt].x = bs; acc[nt].y = bs; acc[nt].z = bs; acc[nt].w = bs;
    }
    layer64(xp, WB, FRAG_IEW2, l, acc);
    {
      bf16x8 ah, al;
      mkA_lds(tg + c * 36 + g * 8, ah, al);
#pragma unroll
      for (int nt = 0; nt < 4; ++nt)
        acc[nt] = mfma_bb(ah, al, WB, FRAG_PECW + nt, l, acc[nt]);
    }
    __builtin_amdgcn_wave_barrier();
    epi_pack(l, acc, xp, nullptr, nullptr, false);
    __builtin_amdgcn_wave_barrier();

    // pm1: 64->64, bn, relu
#pragma unroll
    for (int nt = 0; nt < 4; ++nt) {
      float bs = W[WOFF_PMB1 + nt * 16 + c];
      acc[nt].x = bs; acc[nt].y = bs; acc[nt].z = bs; acc[nt].w = bs;
    }
    layer64(xp, WB, FRAG_PMW1, l, acc);
    __builtin_amdgcn_wave_barrier();
    epi_pack(l, acc, xp, W + WOFF_PMG1, W + WOFF_PMT1, true);
    __builtin_amdgcn_wave_barrier();

    // pm2: 64->64, bn, relu
#pragma unroll
    for (int nt = 0; nt < 4; ++nt) {
      float bs = W[WOFF_PMB2 + nt * 16 + c];
      acc[nt].x = bs; acc[nt].y = bs; acc[nt].z = bs; acc[nt].w = bs;
    }
    layer64(xp, WB, FRAG_PMW2, l, acc);
    __builtin_amdgcn_wave_barrier();
    epi_pack(l, acc, xp, W + WOFF_PMG2, W + WOFF_PMT2, true);
    __builtin_amdgcn_wave_barrier();

    // pm3: 64->32, bn (no relu), stays in regs
    f32x4 a3[2];
#pragma unroll
    for (int nt = 0; nt < 2; ++nt) {
      float bs = W[WOFF_PMB3 + nt * 16 + c];
      a3[nt].x = bs; a3[nt].y = bs; a3[nt].z = bs; a3[nt].w = bs;
    }
    {
      bf16x8 ah0, al0, ah1, al1;
      mkA_lds(xp + c * 68 + g * 8, ah0, al0);
      mkA_lds(xp + c * 68 + 32 + g * 8, ah1, al1);
#pragma unroll
      for (int nt = 0; nt < 2; ++nt) {
        a3[nt] = mfma_bb(ah0, al0, WB, FRAG_PMW3 + nt, l, a3[nt]);
        a3[nt] = mfma_bb(ah1, al1, WB, FRAG_PMW3 + 2 + nt, l, a3[nt]);
      }
    }
#pragma unroll
    for (int nt = 0; nt < 2; ++nt) {
      float gv = W[WOFF_PMG3 + nt * 16 + c];
      float bv = W[WOFF_PMT3 + nt * 16 + c];
#pragma unroll
      for (int r = 0; r < 4; ++r) a3[nt][r] = fmaf(a3[nt][r], gv, bv);
    }

    // pm4 dot (per-lane 2-ch partial, 16-lane butterfly) + bn
    f32x4 a4r;
    {
      float w4a = W[WOFF_PMW4 + c];
      float w4b = W[WOFF_PMW4 + 16 + c];
      f32x4 pr;
#pragma unroll
      for (int r = 0; r < 4; ++r) pr[r] = fmaf(a3[1][r], w4b, a3[0][r] * w4a);
#pragma unroll
      for (int s = 1; s < 16; s <<= 1) {
#pragma unroll
        for (int r = 0; r < 4; ++r) pr[r] += __shfl_xor(pr[r], s);
      }
      float b4 = W[WOFF_PMB4], g4 = W[WOFF_PMG4], t4 = W[WOFF_PMT4];
      f32x4 lg;
#pragma unroll
      for (int r = 0; r < 4; ++r) lg[r] = fmaf(pr[r] + b4, g4, t4);

      // softmax over 16 neighbors (samples): group g holds samples 4g+r
      float m = fmaxf(fmaxf(lg[0], lg[1]), fmaxf(lg[2], lg[3]));
#pragma unroll
      for (int s = 16; s < 64; s <<= 1) m = fmaxf(m, __shfl_xor(m, s));
      f32x4 e;
      float ssum = 0.f;
#pragma unroll
      for (int r = 0; r < 4; ++r) { e[r] = expf(lg[r] - m); ssum += e[r]; }
#pragma unroll
      for (int s = 16; s < 64; s <<= 1) ssum += __shfl_xor(ssum, s);
#pragma unroll
      for (int r = 0; r < 4; ++r) a4r[r] = e[r] / ssum;
    }
    __builtin_amdgcn_wave_barrier();   // xp reads (pm3) complete before chains overwrite

    // ======== feature chains (original k_feat body) ========
    // gp2 fragments (layer-a k-steps 2,3): per-sample row idxv
    bf16x8 p2h[2], p2l[2];
    {
      const unsigned int* qr = P2T + ((size_t)b * NPTS + idxv) * 64;
#pragma unroll
      for (int ks = 0; ks < 2; ++ks) {
        u32x4 qa = *(const u32x4*)(qr + ks * 32 + g * 8);
        u32x4 qb = *(const u32x4*)(qr + ks * 32 + g * 8 + 4);
        mkA_pk(qa, qb, p2h[ks], p2l[ks]);
      }
    }

    // ---- layer a: [gp1|gp2](128) -> 64 ----
    {
      const float* Ba = W + (which == 0 ? WOFF_CB1A : WOFF_CB2A);
      int fa = (which == 0) ? FRAG_C1A : FRAG_C2A;
#pragma unroll
      for (int nt = 0; nt < 4; ++nt) {
        float bs = Ba[nt * 16 + c];
        acc[nt].x = bs; acc[nt].y = bs; acc[nt].z = bs; acc[nt].w = bs;
      }
#pragma unroll
      for (int nt = 0; nt < 4; ++nt) {
        acc[nt] = mfma_bb(p1h[0], p1l[0], WB, fa + nt, l, acc[nt]);
        acc[nt] = mfma_bb(p1h[1], p1l[1], WB, fa + 4 + nt, l, acc[nt]);
        acc[nt] = mfma_bb(p2h[0], p2l[0], WB, fa + 8 + nt, l, acc[nt]);
        acc[nt] = mfma_bb(p2h[1], p2l[1], WB, fa + 12 + nt, l, acc[nt]);
      }
    }
    __builtin_amdgcn_wave_barrier();
    epi_lrelu(l, acc, xp);
    __builtin_amdgcn_wave_barrier();

    // ---- layer b: 64 -> 64 ----
    {
      const float* Bb = W + (which == 0 ? WOFF_CB1B : WOFF_CB2B);
      int fb = (which == 0) ? FRAG_C1B : FRAG_C2B;
      bf16x8 ah0, al0, ah1, al1;
      mkA_lds(xp + c * 68 + g * 8, ah0, al0);
      mkA_lds(xp + c * 68 + 32 + g * 8, ah1, al1);
#pragma unroll
      for (int nt = 0; nt < 4; ++nt) {
        float bs = Bb[nt * 16 + c];
        acc[nt].x = bs; acc[nt].y = bs; acc[nt].z = bs; acc[nt].w = bs;
        acc[nt] = mfma_bb(ah0, al0, WB, fb + nt, l, acc[nt]);
        acc[nt] = mfma_bb(ah1, al1, WB, fb + 4 + nt, l, acc[nt]);
      }
    }
    __builtin_amdgcn_wave_barrier();

    if (which == 1) {
      // ---- cw3a: A = [lrelu(f2)(cols 0..63) | pd(64..66) | 0] (weights permuted) ----
      epi_lrelu(l, acc, xp);
      if (g == 0) {
        xp[c * 68 + 64] = packbf(pdx);
        xp[c * 68 + 65] = packbf(pdy);
        xp[c * 68 + 66] = packbf(pdz);
        xp[c * 68 + 67] = 0u;
      }
      __builtin_amdgcn_wave_barrier();
      {
        bf16x8 ah0, al0, ah1, al1, ah2, al2;
        mkA_lds(xp + c * 68 + g * 8, ah0, al0);
        mkA_lds(xp + c * 68 + 32 + g * 8, ah1, al1);
        u32x4 qa3 = z4;
        if (g == 0) qa3 = *(const u32x4*)(xp + c * 68 + 64);
        mkA_pk(qa3, z4, ah2, al2);
#pragma unroll
        for (int nt = 0; nt < 4; ++nt) {
          float bs = W[WOFF_CB3A + nt * 16 + c];
          acc[nt].x = bs; acc[nt].y = bs; acc[nt].z = bs; acc[nt].w = bs;
          acc[nt] = mfma_bb(ah0, al0, WB, FRAG_C3A + nt, l, acc[nt]);
          acc[nt] = mfma_bb(ah1, al1, WB, FRAG_C3A + 4 + nt, l, acc[nt]);
          acc[nt] = mfma_bb(ah2, al2, WB, FRAG_C3A + 8 + nt, l, acc[nt]);
        }
      }
      __builtin_amdgcn_wave_barrier();
      epi_lrelu(l, acc, xp);
      __builtin_amdgcn_wave_barrier();
      // ---- cw3b: 64 -> 64 ----
      {
        bf16x8 ah0, al0, ah1, al1;
        mkA_lds(xp + c * 68 + g * 8, ah0, al0);
        mkA_lds(xp + c * 68 + 32 + g * 8, ah1, al1);
#pragma unroll
        for (int nt = 0; nt < 4; ++nt) {
          float bs = W[WOFF_CB3B + nt * 16 + c];
          acc[nt].x = bs; acc[nt].y = bs; acc[nt].z = bs; acc[nt].w = bs;
          acc[nt] = mfma_bb(ah0, al0, WB, FRAG_C3B + nt, l, acc[nt]);
          acc[nt] = mfma_bb(ah1, al1, WB, FRAG_C3B + 4 + nt, l, acc[nt]);
        }
      }
      __builtin_amdgcn_wave_barrier();
    }

    // ---- weighted sum over 16 neighbors -> cost row, stage to costb ----
    {
#pragma unroll
      for (int nt = 0; nt < 4; ++nt) {
        float s = lrelu(acc[nt][0]) * a4r.x;
        s = fmaf(lrelu(acc[nt][1]), a4r.y, s);
        s = fmaf(lrelu(acc[nt][2]), a4r.z, s);
        s = fmaf(lrelu(acc[nt][3]), a4r.w, s);
        s += __shfl_xor(s, 16);
        s += __shfl_xor(s, 32);
        if (g == 0) costb[wv][which * 64 + nt * 16 + c] = packbf(s);
      }
    }
    __builtin_amdgcn_wave_barrier();
  }
  __syncthreads();

  // ---- chain4 layer a: batch-4 points (A rows 0..3), n-tile = wv ----
  f32x4 a4;
  {
    float bs = W[WOFF_CB4A + wv * 16 + c];
    a4.x = bs; a4.y = bs; a4.z = bs; a4.w = bs;
#pragma unroll
    for (int ks = 0; ks < 4; ++ks) {
      u32x4 qa = z4, qb = z4;
      if (c < 4) {
        qa = *(const u32x4*)(&costb[c][ks * 32 + g * 8]);
        qb = *(const u32x4*)(&costb[c][ks * 32 + g * 8 + 4]);
      }
      bf16x8 ah, al;
      mkA_pk(qa, qb, ah, al);
      a4 = mfma_bb(ah, al, WB, FRAG_C4A + ks * 4 + wv, l, a4);
    }
  }
  if (g == 0) {
#pragma unroll
    for (int r = 0; r < 4; ++r) u4b[r][wv * 16 + c] = packbf(lrelu(a4[r]));
  }
  __syncthreads();

  // ---- chain4 layer b + output ----
  {
    float bs = W[WOFF_CB4B + wv * 16 + c];
    a4.x = bs; a4.y = bs; a4.z = bs; a4.w = bs;
#pragma unroll
    for (int ks = 0; ks < 2; ++ks) {
      u32x4 qa = z4, qb = z4;
      if (c < 4) {
        qa = *(const u32x4*)(&u4b[c][ks * 32 + g * 8]);
        qb = *(const u32x4*)(&u4b[c][ks * 32 + g * 8 + 4]);
      }
      bf16x8 ah, al;
      mkA_pk(qa, qb, ah, al);
      a4 = mfma_bb(ah, al, WB, FRAG_C4B + ks * 4 + wv, l, a4);
    }
  }
  if (g == 0) {
    int n0 = (blockIdx.x * 4) & (NPTS - 1);
    int b0 = (blockIdx.x * 4) >> 13;
    size_t ob = (size_t)b0 * 64 * NPTS + (size_t)(wv * 16 + c) * NPTS + n0;
#pragma unroll
    for (int r = 0; r < 4; ++r) stout(out, ob + r, lrelu(a4[r]), f32);
  }
}

// ---------------- host ----------------
extern "C" void kernel_launch(void* const* d_in, const int* in_sizes, int n_in,
                              void* d_out, int out_size, void* d_ws, size_t ws_size,
                              hipStream_t stream) {
  (void)in_sizes; (void)n_in; (void)out_size; (void)ws_size;
  float*  W    = (float*)d_ws;
  int*    FLAG = (int*)((char*)d_ws + BOFF_FLAG);
  float4* PK   = (float4*)((char*)d_ws + BOFF_PK);
  unsigned int* WBu = (unsigned int*)((char*)d_ws + BOFF_WB);
  int*    IDX  = (int*)((char*)d_ws + BOFF_IDX);
  unsigned int* P1T = (unsigned int*)((char*)d_ws + BOFF_P1T);
  unsigned int* P2T = (unsigned int*)((char*)d_ws + BOFF_P2T);
  unsigned short* PART = (unsigned short*)((char*)d_ws + BOFF_PART);

  static const int WOFFS[40] = {
    WOFF_CW1A, WOFF_CB1A, WOFF_CW1B, WOFF_CB1B,
    WOFF_CW2A, WOFF_CB2A, WOFF_CW2B, WOFF_CB2B,
    WOFF_CW3A, WOFF_CB3A, WOFF_CW3B, WOFF_CB3B,
    WOFF_CW4A, WOFF_CB4A, WOFF_CW4B, WOFF_CB4B,
    WOFF_IEW1, WOFF_IEB1, WOFF_IEG,  WOFF_IEBT,
    WOFF_IEW2, WOFF_IEB2, WOFF_PECW, WOFF_PECB,
    WOFF_PMW1, WOFF_PMB1, WOFF_PMG1, WOFF_PMT1,
    WOFF_PMW2, WOFF_PMB2, WOFF_PMG2, WOFF_PMT2,
    WOFF_PMW3, WOFF_PMB3, WOFF_PMG3, WOFF_PMT3,
    WOFF_PMW4, WOFF_PMB4, WOFF_PMG4, WOFF_PMT4};
  static const int WNS[40] = {
    8192, 64, 4096, 64,  8192, 64, 4096, 64,  4288, 64, 4096, 64,
    8192, 64, 4096, 64,  192, 64, 64, 64,  4096, 64,  1536, 64,
    4096, 64, 64, 64,  4096, 64, 64, 64,  2048, 32, 32, 32,  32, 1, 1, 1};

  PrepTab tab;
  for (int a = 0; a < 40; ++a) {
    tab.src[a] = d_in[6 + a];
    tab.off[a] = WOFFS[a];
    tab.n[a] = WNS[a];
    tab.scale[a] = 1.f;
  }
  tab.scale[18] = C_IE;                               // ie_g
  tab.scale[26] = C_PM; tab.scale[30] = C_PM;         // pm_g1, pm_g2
  tab.scale[34] = C_PM; tab.scale[38] = C_PM;         // pm_g3, pm_g4

  // fragment table: frag f = fb[m] + ks*(N/16) + nt
  WTab wt;
  {
    int f = 0, m = 0;
    auto add = [&](int woff, int N, int nks, int kreal, int mode) {
      wt.woff[m] = woff; wt.nn[m] = N; wt.kreal[m] = kreal;
      wt.mode[m] = mode; wt.fb[m] = f;
      f += nks * (N / 16); ++m;
    };
    add(WOFF_IEW2, 64, 2, 64, 0);    // 0..7
    add(WOFF_PECW, 64, 1, 24, 0);    // 8..11
    add(WOFF_PMW1, 64, 2, 64, 0);    // 12..19
    add(WOFF_PMW2, 64, 2, 64, 0);    // 20..27
    add(WOFF_PMW3, 32, 2, 64, 0);    // 28..31
    add(WOFF_CW1A, 64, 4, 128, 0);   // 32..47
    add(WOFF_CW1B, 64, 2, 64, 0);    // 48..55
    add(WOFF_CW2A, 64, 4, 128, 0);   // 56..71
    add(WOFF_CW2B, 64, 2, 64, 0);    // 72..79
    add(WOFF_CW3A, 64, 3, 67, 1);    // 80..91 (row-permuted [f2|pd|0])
    add(WOFF_CW3B, 64, 2, 64, 0);    // 92..99
    add(WOFF_CW4A, 64, 4, 128, 0);   // 100..115
    add(WOFF_CW4B, 64, 2, 64, 0);    // 116..123
    wt.nm = m;
  }

  k_detect<<<dim3(1), dim3(64), 0, stream>>>(d_in[3], FLAG);
  k_prep<<<dim3(40), dim3(256), 0, stream>>>(tab, W, FLAG);
  k_wbprep<<<dim3(NFRAG), dim3(64), 0, stream>>>(wt, W, WBu);
  k_pack<<<dim3(64), dim3(256), 0, stream>>>(d_in[0], d_in[1], d_in[2], d_in[5], PK, FLAG);
  k_knnp<<<dim3(NPTS / 256, BATCH, 2 * NPART), dim3(256), 0, stream>>>(PK, PART);
  k_merge<<<dim3(2 * BN / 256), dim3(256), 0, stream>>>(PK, PART, IDX);
  // transposes AFTER merge: PART aliases P1T/P2T
  k_tr<<<dim3(NPTS / 64, BATCH), dim3(64), 0, stream>>>(d_in[3], P1T, FLAG);
  k_tr<<<dim3(NPTS / 64, BATCH), dim3(64), 0, stream>>>(d_in[4], P2T, FLAG);
  k_feat<<<dim3(BN / 4), dim3(256), 0, stream>>>(P1T, P2T, W, WBu, IDX, PK, d_out, FLAG);
}

// Round 10
// 1537.939 us; speedup vs baseline: 1.3739x; 1.3739x over previous
//
#include <hip/hip_runtime.h>
#include <hip/hip_bf16.h>
#include <math.h>

typedef __hip_bfloat16 bf16;

#define NPTS  8192
#define BATCH 2
#define KNB   16
#define NPART 16
#define PARTC (NPTS / NPART)   // 512
#define CAP   24               // knn pass-2 capture buffer per thread
#define BN    (BATCH * NPTS)

#define C_IE 0.9999950000374997f   // 1/sqrt(1+1e-5)
#define C_PM 0.9995003746877732f   // 1/sqrt(1+1e-3)

// ---- weight block float offsets inside ws ----
enum {
  WOFF_CW1A = 0,     WOFF_CB1A = 8192,  WOFF_CW1B = 8256,  WOFF_CB1B = 12352,
  WOFF_CW2A = 12416, WOFF_CB2A = 20608, WOFF_CW2B = 20672, WOFF_CB2B = 24768,
  WOFF_CW3A = 24832, WOFF_CB3A = 29120, WOFF_CW3B = 29184, WOFF_CB3B = 33280,
  WOFF_CW4A = 33344, WOFF_CB4A = 41536, WOFF_CW4B = 41600, WOFF_CB4B = 45696,
  WOFF_IEW1 = 45760, WOFF_IEB1 = 45952, WOFF_IEG  = 46016, WOFF_IEBT = 46080,
  WOFF_IEW2 = 46144, WOFF_IEB2 = 50240, WOFF_PECW = 50304, WOFF_PECB = 51840,
  WOFF_PMW1 = 51904, WOFF_PMB1 = 56000, WOFF_PMG1 = 56064, WOFF_PMT1 = 56128,
  WOFF_PMW2 = 56192, WOFF_PMB2 = 60288, WOFF_PMG2 = 60352, WOFF_PMT2 = 60416,
  WOFF_PMW3 = 60480, WOFF_PMB3 = 62528, WOFF_PMG3 = 62560, WOFF_PMT3 = 62592,
  WOFF_PMW4 = 62624, WOFF_PMB4 = 62656, WOFF_PMG4 = 62657, WOFF_PMT4 = 62658
};

// ---- ws byte offsets (unchanged known-good footprint; AW slot now unused) ----
#define BOFF_W    0u
#define BOFF_FLAG 262144u
#define BOFF_PK   262160u     // 4 x [B*N] float4 (1 MB)
#define BOFF_WB   1310736u    // MFMA weight frags: 124 x 64 lanes x 32 B = 248 KB
#define BOFF_IDX  2359312u    // final idx [2][B][N][16] i32 (2 MB)
#define BOFF_AW   4456464u    // (unused after logit/feat fusion)
#define BOFF_P1T  5505040u    // points1^T packed hi|lo u32 [B][N][64] (4 MB)
#define BOFF_P2T  9699344u    // points2^T packed hi|lo u32 [B][N][64] (4 MB)
#define BOFF_PART BOFF_P1T    // knn partials aliased over P1T/P2T+slack; k_tr after k_merge

typedef __attribute__((ext_vector_type(4))) float f32x4;
typedef __attribute__((ext_vector_type(8))) short bf16x8;
typedef __attribute__((ext_vector_type(4))) unsigned int u32x4;

__device__ __forceinline__ float lrelu(float v) { return v > 0.f ? v : 0.1f * v; }

__device__ __forceinline__ float ldin(const void* p, size_t i, int f32) {
  return f32 ? ((const float*)p)[i] : __bfloat162float(((const bf16*)p)[i]);
}
__device__ __forceinline__ void stout(void* p, size_t i, float v, int f32) {
  if (f32) ((float*)p)[i] = v;
  else ((bf16*)p)[i] = __float2bfloat16(v);
}

// bf16 round-nearest-even split: x ~= hi + lo (hi,lo bf16 bit patterns)
__device__ __forceinline__ unsigned int bf16rne(float x) {
  unsigned int u = __float_as_uint(x);
  return (u + 0x7fffu + ((u >> 16) & 1u)) >> 16;
}
__device__ __forceinline__ void splitbf(float x, unsigned int& h, unsigned int& l) {
  h = bf16rne(x);
  float hf = __uint_as_float(h << 16);
  l = bf16rne(x - hf);
}
__device__ __forceinline__ unsigned int packbf(float v) {
  unsigned int h, lo;
  splitbf(v, h, lo);
  return h | (lo << 16);
}

// stable top-16 insertion (keeps lower index on ties when fed ascending j)
__device__ __forceinline__ void insert16(float d, int id, float* best, int* bidx) {
#pragma unroll
  for (int p = 0; p < KNB; ++p) {
    bool c = d < best[p];
    float tb = best[p]; int ti = bidx[p];
    best[p] = c ? d : tb; bidx[p] = c ? id : ti;
    d = c ? tb : d; id = c ? ti : id;
  }
}

// one bitonic compare-exchange pass over a 16-float register array.
// J,K are literal constants -> indices fold to constants, array stays in regs.
#define BPASS(arr, J, K) \
  _Pragma("unroll") \
  for (int i = 0; i < 16; ++i) { \
    int ix = i ^ (J); \
    if (ix > i) { \
      float lo = fminf(arr[i], arr[ix]); \
      float hi = fmaxf(arr[i], arr[ix]); \
      if ((i & (K)) == 0) { arr[i] = lo; arr[ix] = hi; } \
      else { arr[i] = hi; arr[ix] = lo; } \
    } \
  }

// exact reference distance chain (bit-replicates f32 expanded form)
__device__ __forceinline__ float qsq(float4 qv) {
  return __fadd_rn(__fadd_rn(__fmul_rn(qv.x, qv.x), __fmul_rn(qv.y, qv.y)),
                   __fmul_rn(qv.z, qv.z));
}
__device__ __forceinline__ float refdist(float4 qv, float sq, float4 rv) {
  float sr = qsq(rv);
  float dot = __fmaf_rn(qv.z, rv.z, __fmaf_rn(qv.y, rv.y, __fmul_rn(qv.x, rv.x)));
  return __fsub_rn(__fadd_rn(sq, sr), __fadd_rn(dot, dot));
}
__device__ __forceinline__ float refdist_sr(float4 qv, float sq, float4 rv) {
  float dot = __fmaf_rn(qv.z, rv.z, __fmaf_rn(qv.y, rv.y, __fmul_rn(qv.x, rv.x)));
  return __fsub_rn(__fadd_rn(sq, rv.w), __fadd_rn(dot, dot));
}

// ---------------- dtype autodetect ----------------
__global__ void k_detect(const void* __restrict__ pts1, int* __restrict__ flag) {
  int tid = threadIdx.x;  // 64
  const bf16* p = (const bf16*)pts1;
  int cnt = 0;
  for (int i = tid; i < 1024; i += 64) {
    float v = __bfloat162float(p[i]);
    if (!(fabsf(v) <= 64.f)) cnt++;
  }
#pragma unroll
  for (int s = 32; s; s >>= 1) cnt += __shfl_down(cnt, s);
  if (tid == 0) *flag = (cnt >= 8) ? 1 : 0;
}

// ---------------- prep ----------------
struct PrepTab {
  const void* src[40];
  int off[40];
  int n[40];
  float scale[40];
};

__global__ void k_prep(PrepTab tab, float* __restrict__ W, const int* __restrict__ flag) {
  int f32 = *flag;
  int a = blockIdx.x;
  const void* s = tab.src[a];
  float* d = W + tab.off[a];
  float sc = tab.scale[a];
  for (int i = threadIdx.x; i < tab.n[a]; i += blockDim.x) d[i] = ldin(s, i, f32) * sc;
}

// ---------------- MFMA weight fragment prep ----------------
// frag f: 64 lanes x {hi float4(8 bf16), lo float4}. B-layout: lane l holds
// W[srck(ks*32+(l>>4)*8+e)][nt*16+(l&15)], word r = elem2r | elem2r+1<<16.
// mode 0: srck = k (<kreal else 0). mode 1 (cw3a): A=[f2(64)|pd(3)|0]:
//   k<64 -> k+3; 64..66 -> k-64; else 0.
struct WTab { int woff[16]; int nn[16]; int kreal[16]; int mode[16]; int fb[16]; int nm; };

__global__ __launch_bounds__(64) void k_wbprep(WTab wt, const float* __restrict__ W,
                                               unsigned int* __restrict__ WB) {
  int f = blockIdx.x, l = threadIdx.x;
  int m = 0;
  for (int i = 1; i < wt.nm; ++i)
    if (wt.fb[i] <= f) m = i;
  int ntile = wt.nn[m] >> 4;
  int local = f - wt.fb[m];
  int ks = local / ntile, nt = local - ks * ntile;
  int g = l >> 4, c = l & 15;
  int col = nt * 16 + c;
  int N = wt.nn[m], kr = wt.kreal[m], wo = wt.woff[m], mode = wt.mode[m];
  unsigned int hw[4], lw[4];
#pragma unroll
  for (int r = 0; r < 4; ++r) {
    float wv2[2];
#pragma unroll
    for (int e = 0; e < 2; ++e) {
      int k = ks * 32 + g * 8 + 2 * r + e;
      int srck;
      if (mode == 1) srck = (k < 64) ? k + 3 : ((k < 67) ? k - 64 : -1);
      else srck = (k < kr) ? k : -1;
      wv2[e] = (srck >= 0) ? W[wo + srck * N + col] : 0.f;
    }
    unsigned int h0, l0, h1, l1;
    splitbf(wv2[0], h0, l0);
    splitbf(wv2[1], h1, l1);
    hw[r] = h0 | (h1 << 16);
    lw[r] = l0 | (l1 << 16);
  }
  unsigned int* d = WB + ((size_t)f * 64 + l) * 8;
  d[0] = hw[0]; d[1] = hw[1]; d[2] = hw[2]; d[3] = hw[3];
  d[4] = lw[0]; d[5] = lw[1]; d[6] = lw[2]; d[7] = lw[3];
}

// ---------------- pack (w = qsq, bit-identical chain to the old tile staging) --
__global__ void k_pack(const void* __restrict__ xyz1, const void* __restrict__ xyz2,
                       const void* __restrict__ xyz2w, const void* __restrict__ sf,
                       float4* __restrict__ pk, const int* __restrict__ flag) {
  int f32 = *flag;
  int t = blockIdx.x * 256 + threadIdx.x;  // B*N
  int b = t >> 13, n = t & (NPTS - 1);
  size_t base = (size_t)b * 3 * NPTS + n;
  float ax = ldin(xyz1, base, f32), ay = ldin(xyz1, base + NPTS, f32), az = ldin(xyz1, base + 2 * NPTS, f32);
  float sx = ldin(sf, base, f32),   sy = ldin(sf, base + NPTS, f32),   sz = ldin(sf, base + 2 * NPTS, f32);
  float4 p0 = make_float4(__fadd_rn(ax, sx), __fadd_rn(ay, sy), __fadd_rn(az, sz), 0.f);
  p0.w = qsq(p0);
  float4 p1 = make_float4(ax, ay, az, 0.f);
  p1.w = qsq(p1);
  float4 p2 = make_float4(ldin(xyz2, base, f32), ldin(xyz2, base + NPTS, f32), ldin(xyz2, base + 2 * NPTS, f32), 0.f);
  p2.w = qsq(p2);
  float4 p3 = make_float4(ldin(xyz2w, base, f32), ldin(xyz2w, base + NPTS, f32), ldin(xyz2w, base + 2 * NPTS, f32), 0.f);
  p3.w = qsq(p3);
  pk[t]          = p0;
  pk[t + BN]     = p1;
  pk[t + 2 * BN] = p2;
  pk[t + 3 * BN] = p3;
}

// ---------------- transpose (writes packed hi|lo u32) ----------------
__global__ __launch_bounds__(64) void k_tr(const void* __restrict__ src,
                                           unsigned int* __restrict__ dst,
                                           const int* __restrict__ flag) {
  __shared__ float tile[64][65];
  int f32 = *flag;
  int tid = threadIdx.x;
  int n0 = blockIdx.x * 64;
  int b = blockIdx.y;
  for (int i = 0; i < 64; ++i)
    tile[i][tid] = ldin(src, ((size_t)b * 64 + i) * NPTS + n0 + tid, f32);
  __syncthreads();
  for (int i = 0; i < 64; ++i)
    dst[((size_t)b * NPTS + n0 + i) * 64 + tid] = packbf(tile[tid][i]);
}

// ---------------- KNN partials: scalar-broadcast ref reads (no LDS tile) -----
__global__ __launch_bounds__(256) void k_knnp(const float4* __restrict__ pk,
                                              unsigned short* __restrict__ part_idx) {
  __shared__ unsigned short sbuf[256 * CAP];
  int tid = threadIdx.x;
  int n = blockIdx.x * 256 + tid;
  int b = blockIdx.y;
  int which = blockIdx.z >> 4;   // NPART==16
  int part  = blockIdx.z & 15;
  const float4* q = pk + (size_t)which * BN;
  const float4* r = pk + (size_t)(2 + which) * BN + (size_t)b * NPTS;
  float4 qv = q[b * NPTS + n];
  float sq = qsq(qv);

  float best[KNB];
#pragma unroll
  for (int p = 0; p < KNB; ++p) best[p] = 3.4e38f;   // sorted asc (all equal)

  const int c0 = part * PARTC;
  // pass 1: exact 16 smallest distance VALUES (batched bitonic)
  for (int t = 0; t < PARTC / 16; ++t) {
    const float4* rr = r + c0 + t * 16;   // uniform across the wave
    float fr[16];
#pragma unroll
    for (int j = 0; j < 16; ++j) fr[j] = refdist_sr(qv, sq, rr[j]);
    // bitonic sort fr ascending (10 passes)
    BPASS(fr, 1, 2)
    BPASS(fr, 2, 4) BPASS(fr, 1, 4)
    BPASS(fr, 4, 8) BPASS(fr, 2, 8) BPASS(fr, 1, 8)
    BPASS(fr, 8, 16) BPASS(fr, 4, 16) BPASS(fr, 2, 16) BPASS(fr, 1, 16)
    // min-merge: keep 16 smallest of best(asc) U fr(asc) -> bitonic in best
#pragma unroll
    for (int i = 0; i < 16; ++i) best[i] = fminf(best[i], fr[15 - i]);
    // bitonic cleanup -> best sorted asc again (K=16: all-ascending passes)
    BPASS(best, 8, 16) BPASS(best, 4, 16) BPASS(best, 2, 16) BPASS(best, 1, 16)
  }
  float thr = best[KNB - 1];

  // pass 2: capture candidate indices with dd <= thr (ascending global index)
  int cnt = 0;
  for (int t = 0; t < PARTC / 16; ++t) {
    const float4* rr = r + c0 + t * 16;   // uniform across the wave
#pragma unroll
    for (int j = 0; j < 16; ++j) {
      float dd = refdist_sr(qv, sq, rr[j]);
      if (dd <= thr && cnt < CAP) {
        sbuf[tid * CAP + cnt] = (unsigned short)(c0 + t * 16 + j);
        cnt++;
      }
    }
  }

  // post: exact (d, idx) selection among <=CAP captured
  float bd[KNB]; int bi[KNB];
#pragma unroll
  for (int p = 0; p < KNB; ++p) { bd[p] = 3.4e38f; bi[p] = 0; }
  for (int m = 0; m < CAP; ++m) {
    if (m < cnt) {
      int id = sbuf[tid * CAP + m];
      float dd = refdist(qv, sq, r[id]);
      insert16(dd, id, bd, bi);
    }
  }
  size_t o = ((((size_t)which * BATCH + b) * NPART + part) * NPTS + n) * KNB;
#pragma unroll
  for (int p = 0; p < KNB; ++p) part_idx[o + p] = (unsigned short)bi[p];
}

// ---------------- KNN merge (16 parts x 16 u16 candidates, ascending feed) ----
__global__ void k_merge(const float4* __restrict__ pk,
                        const unsigned short* __restrict__ part_idx,
                        int* __restrict__ idxf) {
  int t = blockIdx.x * 256 + threadIdx.x;  // (which*B+b)*N+n
  int n = t & (NPTS - 1);
  int wb = t >> 13;
  int b = wb & (BATCH - 1);
  int which = wb / BATCH;
  const float4* q = pk + (size_t)which * BN;
  const float4* r = pk + (size_t)(2 + which) * BN + (size_t)b * NPTS;
  float4 qv = q[b * NPTS + n];
  float sq = qsq(qv);
  float best[KNB]; int bidx[KNB];
#pragma unroll
  for (int p = 0; p < KNB; ++p) { best[p] = 3.4e38f; bidx[p] = 0; }
  for (int part = 0; part < NPART; ++part) {
    size_t o = ((((size_t)which * BATCH + b) * NPART + part) * NPTS + n) * KNB;
#pragma unroll
    for (int m = 0; m < KNB; ++m) {
      int id = part_idx[o + m];
      float dd = refdist(qv, sq, r[id]);
      if (dd < best[KNB - 1]) insert16(dd, id, best, bidx);
    }
  }
  size_t oo = (size_t)t * KNB;
#pragma unroll
  for (int p = 0; p < KNB; ++p) idxf[oo + p] = bidx[p];
}

// ---------------- MFMA helpers ----------------
__device__ __forceinline__ bf16x8 mk8(unsigned int w0, unsigned int w1,
                                      unsigned int w2, unsigned int w3) {
  u32x4 u;
  u.x = w0; u.y = w1; u.z = w2; u.w = w3;
  return __builtin_bit_cast(bf16x8, u);
}

// build A hi/lo frags from 8 packed (hi|lo<<16) u32
__device__ __forceinline__ void mkA_pk(u32x4 qa, u32x4 qb, bf16x8& ah, bf16x8& al) {
  unsigned int q0 = qa.x, q1 = qa.y, q2 = qa.z, q3 = qa.w;
  unsigned int q4 = qb.x, q5 = qb.y, q6 = qb.z, q7 = qb.w;
  ah = mk8((q0 & 0xffffu) | (q1 << 16), (q2 & 0xffffu) | (q3 << 16),
           (q4 & 0xffffu) | (q5 << 16), (q6 & 0xffffu) | (q7 << 16));
  al = mk8((q0 >> 16) | (q1 & 0xffff0000u), (q2 >> 16) | (q3 & 0xffff0000u),
           (q4 >> 16) | (q5 & 0xffff0000u), (q6 >> 16) | (q7 & 0xffff0000u));
}
__device__ __forceinline__ void mkA_lds(const unsigned int* p, bf16x8& ah, bf16x8& al) {
  mkA_pk(*(const u32x4*)p, *(const u32x4*)(p + 4), ah, al);
}

#define FRAG_IEW2 0
#define FRAG_PECW 8
#define FRAG_PMW1 12
#define FRAG_PMW2 20
#define FRAG_PMW3 28
#define FRAG_C1A  32
#define FRAG_C1B  48
#define FRAG_C2A  56
#define FRAG_C2B  72
#define FRAG_C3A  80
#define FRAG_C3B  92
#define FRAG_C4A  100
#define FRAG_C4B  116
#define NFRAG     124

// acc += A * Wfrag with split-bf16 3-product emulation
__device__ __forceinline__ f32x4 mfma_bb(bf16x8 ah, bf16x8 al,
                                         const unsigned int* __restrict__ WB,
                                         int f, int lane, f32x4 acc) {
  const u32x4* p = (const u32x4*)WB + ((size_t)(f * 64 + lane)) * 2;
  u32x4 h4 = p[0], l4 = p[1];
  bf16x8 bh = __builtin_bit_cast(bf16x8, h4);
  bf16x8 bl = __builtin_bit_cast(bf16x8, l4);
  acc = __builtin_amdgcn_mfma_f32_16x16x32_bf16(al, bh, acc, 0, 0, 0);
  acc = __builtin_amdgcn_mfma_f32_16x16x32_bf16(ah, bl, acc, 0, 0, 0);
  acc = __builtin_amdgcn_mfma_f32_16x16x32_bf16(ah, bh, acc, 0, 0, 0);
  return acc;
}

// one 64->64 layer: A from xp (sample row = lane&15), 2 k-steps x 4 n-tiles
__device__ __forceinline__ void layer64(const unsigned int* __restrict__ xp,
                                        const unsigned int* __restrict__ WB,
                                        int fbase, int lane, f32x4 acc[4]) {
  int c = lane & 15, g = lane >> 4;
  bf16x8 ah0, al0, ah1, al1;
  mkA_lds(xp + c * 68 + g * 8, ah0, al0);
  mkA_lds(xp + c * 68 + 32 + g * 8, ah1, al1);
#pragma unroll
  for (int nt = 0; nt < 4; ++nt) {
    acc[nt] = mfma_bb(ah0, al0, WB, fbase + nt, lane, acc[nt]);
    acc[nt] = mfma_bb(ah1, al1, WB, fbase + 4 + nt, lane, acc[nt]);
  }
}

// epilogue: optional bn(+relu), split to bf16 hi/lo, pack, write to xp
__device__ __forceinline__ void epi_pack(int lane, f32x4 acc[4], unsigned int* xp,
                                         const float* gw, const float* bw, bool relu) {
  int c = lane & 15, g = lane >> 4;
#pragma unroll
  for (int nt = 0; nt < 4; ++nt) {
    float gv = gw ? gw[nt * 16 + c] : 1.f;
    float bv = gw ? bw[nt * 16 + c] : 0.f;
#pragma unroll
    for (int r = 0; r < 4; ++r) {
      float v = acc[nt][r];
      if (gw) v = fmaf(v, gv, bv);
      if (relu) v = fmaxf(v, 0.f);
      xp[(g * 4 + r) * 68 + nt * 16 + c] = packbf(v);
    }
  }
}

// epilogue with leaky relu (k_feat chains)
__device__ __forceinline__ void epi_lrelu(int lane, f32x4 acc[4], unsigned int* xp) {
  int c = lane & 15, g = lane >> 4;
#pragma unroll
  for (int nt = 0; nt < 4; ++nt) {
#pragma unroll
    for (int r = 0; r < 4; ++r)
      xp[(g * 4 + r) * 68 + nt * 16 + c] = packbf(lrelu(acc[nt][r]));
  }
}

// ---------------- k_feat: fused IPC-logit + chains on matrix cores -----------
// block = 4 waves = 4 points; wave = one point's 16 neighbors (16-sample batch).
// Spill control (r9 lesson: 2 GB scratch traffic): gp1 fragments are loaded
// AFTER the IPC phase (only consumed by chain layer-a), and the attention
// weights cross the phase boundary through a 256 B LDS buffer (f32, identical
// numerics) instead of registers. launch_bounds relaxed to (256,2) for RA room.
__global__ __launch_bounds__(256, 2) void k_feat(const unsigned int* __restrict__ P1T,
                                                 const unsigned int* __restrict__ P2T,
                                                 const float* __restrict__ W,
                                                 const unsigned int* __restrict__ WB,
                                                 const int* __restrict__ idxf,
                                                 const float4* __restrict__ pk,
                                                 void* __restrict__ out,
                                                 const int* __restrict__ flag) {
  __shared__ unsigned int xp_s[4][16 * 68];
  __shared__ unsigned int tg_s[4][16 * 36];  // packed trig rows (24 real + 8 zero)
  __shared__ unsigned int costb[4][132];     // [point][costA(64)|costB(64)] packed
  __shared__ unsigned int u4b[4][68];        // chain4 mid activations [point][64]
  __shared__ float awb[4][16];               // attention weights (phase handoff)
  const int l = threadIdx.x & 63;
  const int wv = threadIdx.x >> 6;
  const int c = l & 15, g = l >> 4;
  unsigned int* xp = xp_s[wv];
  unsigned int* tg = tg_s[wv];
  const int f32 = *flag;
  const int pt = blockIdx.x * 4 + wv;    // b*N+n
  const int n = pt & (NPTS - 1);
  const int b = pt >> 13;
  float4 qp = pk[(size_t)BN + pt];       // x1[n]
  u32x4 z4;
  z4.x = 0u; z4.y = 0u; z4.z = 0u; z4.w = 0u;

  for (int which = 0; which < 2; ++which) {
    int idxv = idxf[(((size_t)which * BATCH + b) * NPTS + n) * KNB + c];
    float4 pv = pk[(size_t)2 * BN + (size_t)b * NPTS + idxv];  // x2[idx]
    float pdx = pv.x - qp.x, pdy = pv.y - qp.y, pdz = pv.z - qp.z;

    // ======== IPC logit MLP (was k_logit) ========
    // trig: 12 sincos per sample, 3 per k-group lane
    {
      unsigned int* tr = tg + c * 36;
#pragma unroll
      for (int j = 0; j < 3; ++j) {
        int t = g * 3 + j;
        int c3 = t >> 2, fq = t & 3;
        float pdc = (c3 == 0) ? pdx : (c3 == 1) ? pdy : pdz;
        float pe = (pdc - rintf(pdc * 4.f) * 0.25f) * 4.f;
        float tt = pe / 1.000001f * 6.28318530717958647692f;
        float dv = (fq == 0) ? 1.f : (fq == 1) ? 10.f : (fq == 2) ? 100.f : 1000.f;
        float sn, cs;
        sincosf(tt / dv, &sn, &cs);
        unsigned int hs, ls2, hc, lc;
        splitbf(sn, hs, ls2);
        splitbf(cs, hc, lc);
        tr[2 * t] = hs | (ls2 << 16);
        tr[2 * t + 1] = hc | (lc << 16);
      }
      if (g == 3) {
#pragma unroll
        for (int z = 24; z < 32; ++z) tr[z] = 0u;
      }
    }

    // ie1: 3->64, bn, relu (exact f32), pack to xp[sample=c][ch]
    {
      unsigned int* xr = xp + c * 68 + g * 16;
#pragma unroll
      for (int m4 = 0; m4 < 4; ++m4) {
        int ch = g * 16 + m4 * 4;
        float4 bb = *(const float4*)(W + WOFF_IEB1 + ch);
        float4 w0 = *(const float4*)(W + WOFF_IEW1 + ch);
        float4 w1 = *(const float4*)(W + WOFF_IEW1 + 64 + ch);
        float4 w2 = *(const float4*)(W + WOFF_IEW1 + 128 + ch);
        float4 gg = *(const float4*)(W + WOFF_IEG + ch);
        float4 bt = *(const float4*)(W + WOFF_IEBT + ch);
        float v0 = fmaf(pdz, w2.x, fmaf(pdy, w1.x, fmaf(pdx, w0.x, bb.x)));
        float v1 = fmaf(pdz, w2.y, fmaf(pdy, w1.y, fmaf(pdx, w0.y, bb.y)));
        float v2 = fmaf(pdz, w2.z, fmaf(pdy, w1.z, fmaf(pdx, w0.z, bb.z)));
        float v3 = fmaf(pdz, w2.w, fmaf(pdy, w1.w, fmaf(pdx, w0.w, bb.w)));
        v0 = fmaxf(fmaf(v0, gg.x, bt.x), 0.f);
        v1 = fmaxf(fmaf(v1, gg.y, bt.y), 0.f);
        v2 = fmaxf(fmaf(v2, gg.z, bt.z), 0.f);
        v3 = fmaxf(fmaf(v3, gg.w, bt.w), 0.f);
        u32x4 pk4;
        pk4.x = packbf(v0); pk4.y = packbf(v1);
        pk4.z = packbf(v2); pk4.w = packbf(v3);
        *(u32x4*)(xr + m4 * 4) = pk4;
      }
    }
    __builtin_amdgcn_wave_barrier();

    f32x4 acc[4];
    // ie2 + pec (accumulated into one f32 acc; init = ie_b2 + pec_b)
#pragma unroll
    for (int nt = 0; nt < 4; ++nt) {
      float bs = W[WOFF_IEB2 + nt * 16 + c] + W[WOFF_PECB + nt * 16 + c];
      acc[nt].x = bs; acc[nt].y = bs; acc[nt].z = bs; acc[nt].w = bs;
    }
    layer64(xp, WB, FRAG_IEW2, l, acc);
    {
      bf16x8 ah, al;
      mkA_lds(tg + c * 36 + g * 8, ah, al);
#pragma unroll
      for (int nt = 0; nt < 4; ++nt)
        acc[nt] = mfma_bb(ah, al, WB, FRAG_PECW + nt, l, acc[nt]);
    }
    __builtin_amdgcn_wave_barrier();
    epi_pack(l, acc, xp, nullptr, nullptr, false);
    __builtin_amdgcn_wave_barrier();

    // pm1: 64->64, bn, relu
#pragma unroll
    for (int nt = 0; nt < 4; ++nt) {
      float bs = W[WOFF_PMB1 + nt * 16 + c];
      acc[nt].x = bs; acc[nt].y = bs; acc[nt].z = bs; acc[nt].w = bs;
    }
    layer64(xp, WB, FRAG_PMW1, l, acc);
    __builtin_amdgcn_wave_barrier();
    epi_pack(l, acc, xp, W + WOFF_PMG1, W + WOFF_PMT1, true);
    __builtin_amdgcn_wave_barrier();

    // pm2: 64->64, bn, relu
#pragma unroll
    for (int nt = 0; nt < 4; ++nt) {
      float bs = W[WOFF_PMB2 + nt * 16 + c];
      acc[nt].x = bs; acc[nt].y = bs; acc[nt].z = bs; acc[nt].w = bs;
    }
    layer64(xp, WB, FRAG_PMW2, l, acc);
    __builtin_amdgcn_wave_barrier();
    epi_pack(l, acc, xp, W + WOFF_PMG2, W + WOFF_PMT2, true);
    __builtin_amdgcn_wave_barrier();

    // pm3: 64->32, bn (no relu), stays in regs
    f32x4 a3[2];
#pragma unroll
    for (int nt = 0; nt < 2; ++nt) {
      float bs = W[WOFF_PMB3 + nt * 16 + c];
      a3[nt].x = bs; a3[nt].y = bs; a3[nt].z = bs; a3[nt].w = bs;
    }
    {
      bf16x8 ah0, al0, ah1, al1;
      mkA_lds(xp + c * 68 + g * 8, ah0, al0);
      mkA_lds(xp + c * 68 + 32 + g * 8, ah1, al1);
#pragma unroll
      for (int nt = 0; nt < 2; ++nt) {
        a3[nt] = mfma_bb(ah0, al0, WB, FRAG_PMW3 + nt, l, a3[nt]);
        a3[nt] = mfma_bb(ah1, al1, WB, FRAG_PMW3 + 2 + nt, l, a3[nt]);
      }
    }
#pragma unroll
    for (int nt = 0; nt < 2; ++nt) {
      float gv = W[WOFF_PMG3 + nt * 16 + c];
      float bv = W[WOFF_PMT3 + nt * 16 + c];
#pragma unroll
      for (int r = 0; r < 4; ++r) a3[nt][r] = fmaf(a3[nt][r], gv, bv);
    }

    // pm4 dot (per-lane 2-ch partial, 16-lane butterfly) + bn + softmax.
    // Result goes to awb LDS (f32, full precision) -> no cross-phase registers.
    {
      float w4a = W[WOFF_PMW4 + c];
      float w4b = W[WOFF_PMW4 + 16 + c];
      f32x4 pr;
#pragma unroll
      for (int r = 0; r < 4; ++r) pr[r] = fmaf(a3[1][r], w4b, a3[0][r] * w4a);
#pragma unroll
      for (int s = 1; s < 16; s <<= 1) {
#pragma unroll
        for (int r = 0; r < 4; ++r) pr[r] += __shfl_xor(pr[r], s);
      }
      float b4 = W[WOFF_PMB4], g4 = W[WOFF_PMG4], t4 = W[WOFF_PMT4];
      f32x4 lg;
#pragma unroll
      for (int r = 0; r < 4; ++r) lg[r] = fmaf(pr[r] + b4, g4, t4);

      // softmax over 16 neighbors (samples): group g holds samples 4g+r
      float m = fmaxf(fmaxf(lg[0], lg[1]), fmaxf(lg[2], lg[3]));
#pragma unroll
      for (int s = 16; s < 64; s <<= 1) m = fmaxf(m, __shfl_xor(m, s));
      f32x4 e;
      float ssum = 0.f;
#pragma unroll
      for (int r = 0; r < 4; ++r) { e[r] = expf(lg[r] - m); ssum += e[r]; }
#pragma unroll
      for (int s = 16; s < 64; s <<= 1) ssum += __shfl_xor(ssum, s);
      if (c < 4) {
        float ev = (c == 0) ? e[0] : (c == 1) ? e[1] : (c == 2) ? e[2] : e[3];
        awb[wv][g * 4 + c] = ev / ssum;
      }
    }
    __builtin_amdgcn_wave_barrier();   // xp/awb handoff before chains

    // ======== feature chains (original k_feat body) ========
    // gp1 fragments (layer-a k-steps 0,1): row n broadcast (loaded late to
    // keep the IPC phase's register pressure down — r9 spill fix)
    bf16x8 p1h[2], p1l[2];
    {
      const unsigned int* pr = P1T + ((size_t)b * NPTS + n) * 64;
#pragma unroll
      for (int ks = 0; ks < 2; ++ks) {
        u32x4 qa = *(const u32x4*)(pr + ks * 32 + g * 8);
        u32x4 qb = *(const u32x4*)(pr + ks * 32 + g * 8 + 4);
        mkA_pk(qa, qb, p1h[ks], p1l[ks]);
      }
    }
    // gp2 fragments (layer-a k-steps 2,3): per-sample row idxv
    bf16x8 p2h[2], p2l[2];
    {
      const unsigned int* qr = P2T + ((size_t)b * NPTS + idxv) * 64;
#pragma unroll
      for (int ks = 0; ks < 2; ++ks) {
        u32x4 qa = *(const u32x4*)(qr + ks * 32 + g * 8);
        u32x4 qb = *(const u32x4*)(qr + ks * 32 + g * 8 + 4);
        mkA_pk(qa, qb, p2h[ks], p2l[ks]);
      }
    }

    // ---- layer a: [gp1|gp2](128) -> 64 ----
    {
      const float* Ba = W + (which == 0 ? WOFF_CB1A : WOFF_CB2A);
      int fa = (which == 0) ? FRAG_C1A : FRAG_C2A;
#pragma unroll
      for (int nt = 0; nt < 4; ++nt) {
        float bs = Ba[nt * 16 + c];
        acc[nt].x = bs; acc[nt].y = bs; acc[nt].z = bs; acc[nt].w = bs;
      }
#pragma unroll
      for (int nt = 0; nt < 4; ++nt) {
        acc[nt] = mfma_bb(p1h[0], p1l[0], WB, fa + nt, l, acc[nt]);
        acc[nt] = mfma_bb(p1h[1], p1l[1], WB, fa + 4 + nt, l, acc[nt]);
        acc[nt] = mfma_bb(p2h[0], p2l[0], WB, fa + 8 + nt, l, acc[nt]);
        acc[nt] = mfma_bb(p2h[1], p2l[1], WB, fa + 12 + nt, l, acc[nt]);
      }
    }
    __builtin_amdgcn_wave_barrier();
    epi_lrelu(l, acc, xp);
    __builtin_amdgcn_wave_barrier();

    // ---- layer b: 64 -> 64 ----
    {
      const float* Bb = W + (which == 0 ? WOFF_CB1B : WOFF_CB2B);
      int fb = (which == 0) ? FRAG_C1B : FRAG_C2B;
      bf16x8 ah0, al0, ah1, al1;
      mkA_lds(xp + c * 68 + g * 8, ah0, al0);
      mkA_lds(xp + c * 68 + 32 + g * 8, ah1, al1);
#pragma unroll
      for (int nt = 0; nt < 4; ++nt) {
        float bs = Bb[nt * 16 + c];
        acc[nt].x = bs; acc[nt].y = bs; acc[nt].z = bs; acc[nt].w = bs;
        acc[nt] = mfma_bb(ah0, al0, WB, fb + nt, l, acc[nt]);
        acc[nt] = mfma_bb(ah1, al1, WB, fb + 4 + nt, l, acc[nt]);
      }
    }
    __builtin_amdgcn_wave_barrier();

    if (which == 1) {
      // ---- cw3a: A = [lrelu(f2)(cols 0..63) | pd(64..66) | 0] (weights permuted) ----
      epi_lrelu(l, acc, xp);
      if (g == 0) {
        xp[c * 68 + 64] = packbf(pdx);
        xp[c * 68 + 65] = packbf(pdy);
        xp[c * 68 + 66] = packbf(pdz);
        xp[c * 68 + 67] = 0u;
      }
      __builtin_amdgcn_wave_barrier();
      {
        bf16x8 ah0, al0, ah1, al1, ah2, al2;
        mkA_lds(xp + c * 68 + g * 8, ah0, al0);
        mkA_lds(xp + c * 68 + 32 + g * 8, ah1, al1);
        u32x4 qa3 = z4;
        if (g == 0) qa3 = *(const u32x4*)(xp + c * 68 + 64);
        mkA_pk(qa3, z4, ah2, al2);
#pragma unroll
        for (int nt = 0; nt < 4; ++nt) {
          float bs = W[WOFF_CB3A + nt * 16 + c];
          acc[nt].x = bs; acc[nt].y = bs; acc[nt].z = bs; acc[nt].w = bs;
          acc[nt] = mfma_bb(ah0, al0, WB, FRAG_C3A + nt, l, acc[nt]);
          acc[nt] = mfma_bb(ah1, al1, WB, FRAG_C3A + 4 + nt, l, acc[nt]);
          acc[nt] = mfma_bb(ah2, al2, WB, FRAG_C3A + 8 + nt, l, acc[nt]);
        }
      }
      __builtin_amdgcn_wave_barrier();
      epi_lrelu(l, acc, xp);
      __builtin_amdgcn_wave_barrier();
      // ---- cw3b: 64 -> 64 ----
      {
        bf16x8 ah0, al0, ah1, al1;
        mkA_lds(xp + c * 68 + g * 8, ah0, al0);
        mkA_lds(xp + c * 68 + 32 + g * 8, ah1, al1);
#pragma unroll
        for (int nt = 0; nt < 4; ++nt) {
          float bs = W[WOFF_CB3B + nt * 16 + c];
          acc[nt].x = bs; acc[nt].y = bs; acc[nt].z = bs; acc[nt].w = bs;
          acc[nt] = mfma_bb(ah0, al0, WB, FRAG_C3B + nt, l, acc[nt]);
          acc[nt] = mfma_bb(ah1, al1, WB, FRAG_C3B + 4 + nt, l, acc[nt]);
        }
      }
      __builtin_amdgcn_wave_barrier();
    }

    // ---- weighted sum over 16 neighbors -> cost row, stage to costb ----
    {
      float4 a4v = *(const float4*)&awb[wv][g * 4];
#pragma unroll
      for (int nt = 0; nt < 4; ++nt) {
        float s = lrelu(acc[nt][0]) * a4v.x;
        s = fmaf(lrelu(acc[nt][1]), a4v.y, s);
        s = fmaf(lrelu(acc[nt][2]), a4v.z, s);
        s = fmaf(lrelu(acc[nt][3]), a4v.w, s);
        s += __shfl_xor(s, 16);
        s += __shfl_xor(s, 32);
        if (g == 0) costb[wv][which * 64 + nt * 16 + c] = packbf(s);
      }
    }
    __builtin_amdgcn_wave_barrier();
  }
  __syncthreads();

  // ---- chain4 layer a: batch-4 points (A rows 0..3), n-tile = wv ----
  f32x4 a4;
  {
    float bs = W[WOFF_CB4A + wv * 16 + c];
    a4.x = bs; a4.y = bs; a4.z = bs; a4.w = bs;
#pragma unroll
    for (int ks = 0; ks < 4; ++ks) {
      u32x4 qa = z4, qb = z4;
      if (c < 4) {
        qa = *(const u32x4*)(&costb[c][ks * 32 + g * 8]);
        qb = *(const u32x4*)(&costb[c][ks * 32 + g * 8 + 4]);
      }
      bf16x8 ah, al;
      mkA_pk(qa, qb, ah, al);
      a4 = mfma_bb(ah, al, WB, FRAG_C4A + ks * 4 + wv, l, a4);
    }
  }
  if (g == 0) {
#pragma unroll
    for (int r = 0; r < 4; ++r) u4b[r][wv * 16 + c] = packbf(lrelu(a4[r]));
  }
  __syncthreads();

  // ---- chain4 layer b + output ----
  {
    float bs = W[WOFF_CB4B + wv * 16 + c];
    a4.x = bs; a4.y = bs; a4.z = bs; a4.w = bs;
#pragma unroll
    for (int ks = 0; ks < 2; ++ks) {
      u32x4 qa = z4, qb = z4;
      if (c < 4) {
        qa = *(const u32x4*)(&u4b[c][ks * 32 + g * 8]);
        qb = *(const u32x4*)(&u4b[c][ks * 32 + g * 8 + 4]);
      }
      bf16x8 ah, al;
      mkA_pk(qa, qb, ah, al);
      a4 = mfma_bb(ah, al, WB, FRAG_C4B + ks * 4 + wv, l, a4);
    }
  }
  if (g == 0) {
    int n0 = (blockIdx.x * 4) & (NPTS - 1);
    int b0 = (blockIdx.x * 4) >> 13;
    size_t ob = (size_t)b0 * 64 * NPTS + (size_t)(wv * 16 + c) * NPTS + n0;
#pragma unroll
    for (int r = 0; r < 4; ++r) stout(out, ob + r, lrelu(a4[r]), f32);
  }
}

// ---------------- host ----------------
extern "C" void kernel_launch(void* const* d_in, const int* in_sizes, int n_in,
                              void* d_out, int out_size, void* d_ws, size_t ws_size,
                              hipStream_t stream) {
  (void)in_sizes; (void)n_in; (void)out_size; (void)ws_size;
  float*  W    = (float*)d_ws;
  int*    FLAG = (int*)((char*)d_ws + BOFF_FLAG);
  float4* PK   = (float4*)((char*)d_ws + BOFF_PK);
  unsigned int* WBu = (unsigned int*)((char*)d_ws + BOFF_WB);
  int*    IDX  = (int*)((char*)d_ws + BOFF_IDX);
  unsigned int* P1T = (unsigned int*)((char*)d_ws + BOFF_P1T);
  unsigned int* P2T = (unsigned int*)((char*)d_ws + BOFF_P2T);
  unsigned short* PART = (unsigned short*)((char*)d_ws + BOFF_PART);

  static const int WOFFS[40] = {
    WOFF_CW1A, WOFF_CB1A, WOFF_CW1B, WOFF_CB1B,
    WOFF_CW2A, WOFF_CB2A, WOFF_CW2B, WOFF_CB2B,
    WOFF_CW3A, WOFF_CB3A, WOFF_CW3B, WOFF_CB3B,
    WOFF_CW4A, WOFF_CB4A, WOFF_CW4B, WOFF_CB4B,
    WOFF_IEW1, WOFF_IEB1, WOFF_IEG,  WOFF_IEBT,
    WOFF_IEW2, WOFF_IEB2, WOFF_PECW, WOFF_PECB,
    WOFF_PMW1, WOFF_PMB1, WOFF_PMG1, WOFF_PMT1,
    WOFF_PMW2, WOFF_PMB2, WOFF_PMG2, WOFF_PMT2,
    WOFF_PMW3, WOFF_PMB3, WOFF_PMG3, WOFF_PMT3,
    WOFF_PMW4, WOFF_PMB4, WOFF_PMG4, WOFF_PMT4};
  static const int WNS[40] = {
    8192, 64, 4096, 64,  8192, 64, 4096, 64,  4288, 64, 4096, 64,
    8192, 64, 4096, 64,  192, 64, 64, 64,  4096, 64,  1536, 64,
    4096, 64, 64, 64,  4096, 64, 64, 64,  2048, 32, 32, 32,  32, 1, 1, 1};

  PrepTab tab;
  for (int a = 0; a < 40; ++a) {
    tab.src[a] = d_in[6 + a];
    tab.off[a] = WOFFS[a];
    tab.n[a] = WNS[a];
    tab.scale[a] = 1.f;
  }
  tab.scale[18] = C_IE;                               // ie_g
  tab.scale[26] = C_PM; tab.scale[30] = C_PM;         // pm_g1, pm_g2
  tab.scale[34] = C_PM; tab.scale[38] = C_PM;         // pm_g3, pm_g4

  // fragment table: frag f = fb[m] + ks*(N/16) + nt
  WTab wt;
  {
    int f = 0, m = 0;
    auto add = [&](int woff, int N, int nks, int kreal, int mode) {
      wt.woff[m] = woff; wt.nn[m] = N; wt.kreal[m] = kreal;
      wt.mode[m] = mode; wt.fb[m] = f;
      f += nks * (N / 16); ++m;
    };
    add(WOFF_IEW2, 64, 2, 64, 0);    // 0..7
    add(WOFF_PECW, 64, 1, 24, 0);    // 8..11
    add(WOFF_PMW1, 64, 2, 64, 0);    // 12..19
    add(WOFF_PMW2, 64, 2, 64, 0);    // 20..27
    add(WOFF_PMW3, 32, 2, 64, 0);    // 28..31
    add(WOFF_CW1A, 64, 4, 128, 0);   // 32..47
    add(WOFF_CW1B, 64, 2, 64, 0);    // 48..55
    add(WOFF_CW2A, 64, 4, 128, 0);   // 56..71
    add(WOFF_CW2B, 64, 2, 64, 0);    // 72..79
    add(WOFF_CW3A, 64, 3, 67, 1);    // 80..91 (row-permuted [f2|pd|0])
    add(WOFF_CW3B, 64, 2, 64, 0);    // 92..99
    add(WOFF_CW4A, 64, 4, 128, 0);   // 100..115
    add(WOFF_CW4B, 64, 2, 64, 0);    // 116..123
    wt.nm = m;
  }

  k_detect<<<dim3(1), dim3(64), 0, stream>>>(d_in[3], FLAG);
  k_prep<<<dim3(40), dim3(256), 0, stream>>>(tab, W, FLAG);
  k_wbprep<<<dim3(NFRAG), dim3(64), 0, stream>>>(wt, W, WBu);
  k_pack<<<dim3(64), dim3(256), 0, stream>>>(d_in[0], d_in[1], d_in[2], d_in[5], PK, FLAG);
  k_knnp<<<dim3(NPTS / 256, BATCH, 2 * NPART), dim3(256), 0, stream>>>(PK, PART);
  k_merge<<<dim3(2 * BN / 256), dim3(256), 0, stream>>>(PK, PART, IDX);
  // transposes AFTER merge: PART aliases P1T/P2T
  k_tr<<<dim3(NPTS / 64, BATCH), dim3(64), 0, stream>>>(d_in[3], P1T, FLAG);
  k_tr<<<dim3(NPTS / 64, BATCH), dim3(64), 0, stream>>>(d_in[4], P2T, FLAG);
  k_feat<<<dim3(BN / 4), dim3(256), 0, stream>>>(P1T, P2T, W, WBu, IDX, PK, d_out, FLAG);
}

// Round 11
// 811.410 us; speedup vs baseline: 2.6040x; 1.8954x over previous
//
#include <hip/hip_runtime.h>
#include <hip/hip_bf16.h>
#include <math.h>

typedef __hip_bfloat16 bf16;

#define NPTS  8192
#define BATCH 2
#define KNB   16
#define NPART 16
#define PARTC (NPTS / NPART)   // 512
#define CAP   24               // knn pass-2 capture buffer per thread
#define BN    (BATCH * NPTS)

#define C_IE 0.9999950000374997f   // 1/sqrt(1+1e-5)
#define C_PM 0.9995003746877732f   // 1/sqrt(1+1e-3)

// ---- weight block float offsets inside ws ----
enum {
  WOFF_CW1A = 0,     WOFF_CB1A = 8192,  WOFF_CW1B = 8256,  WOFF_CB1B = 12352,
  WOFF_CW2A = 12416, WOFF_CB2A = 20608, WOFF_CW2B = 20672, WOFF_CB2B = 24768,
  WOFF_CW3A = 24832, WOFF_CB3A = 29120, WOFF_CW3B = 29184, WOFF_CB3B = 33280,
  WOFF_CW4A = 33344, WOFF_CB4A = 41536, WOFF_CW4B = 41600, WOFF_CB4B = 45696,
  WOFF_IEW1 = 45760, WOFF_IEB1 = 45952, WOFF_IEG  = 46016, WOFF_IEBT = 46080,
  WOFF_IEW2 = 46144, WOFF_IEB2 = 50240, WOFF_PECW = 50304, WOFF_PECB = 51840,
  WOFF_PMW1 = 51904, WOFF_PMB1 = 56000, WOFF_PMG1 = 56064, WOFF_PMT1 = 56128,
  WOFF_PMW2 = 56192, WOFF_PMB2 = 60288, WOFF_PMG2 = 60352, WOFF_PMT2 = 60416,
  WOFF_PMW3 = 60480, WOFF_PMB3 = 62528, WOFF_PMG3 = 62560, WOFF_PMT3 = 62592,
  WOFF_PMW4 = 62624, WOFF_PMB4 = 62656, WOFF_PMG4 = 62657, WOFF_PMT4 = 62658
};

// ---- ws byte offsets (PART u16 x NPART=16 = 16.8 MB from BOFF_PART ==
//      exactly the round-4 known-good extent of i32 x NPART=4) ----
#define BOFF_W    0u
#define BOFF_FLAG 262144u
#define BOFF_PK   262160u     // 4 x [B*N] float4 (1 MB)
#define BOFF_WB   1310736u    // MFMA weight frags: 124 x 64 lanes x 32 B = 248 KB
#define BOFF_IDX  2359312u    // final idx [2][B][N][16] i32 (2 MB)
#define BOFF_AW   4456464u    // attention weights u16 [2][B][N][16] (1 MB)
#define BOFF_P1T  5505040u    // points1^T packed hi|lo u32 [B][N][64] (4 MB)
#define BOFF_P2T  9699344u    // points2^T packed hi|lo u32 [B][N][64] (4 MB)
#define BOFF_PART BOFF_P1T    // knn partials aliased over P1T/P2T+slack; k_tr after k_merge

typedef __attribute__((ext_vector_type(4))) float f32x4;
typedef __attribute__((ext_vector_type(8))) short bf16x8;
typedef __attribute__((ext_vector_type(4))) unsigned int u32x4;

__device__ __forceinline__ float lrelu(float v) { return v > 0.f ? v : 0.1f * v; }

__device__ __forceinline__ float ldin(const void* p, size_t i, int f32) {
  return f32 ? ((const float*)p)[i] : __bfloat162float(((const bf16*)p)[i]);
}
__device__ __forceinline__ void stout(void* p, size_t i, float v, int f32) {
  if (f32) ((float*)p)[i] = v;
  else ((bf16*)p)[i] = __float2bfloat16(v);
}

// bf16 round-nearest-even split: x ~= hi + lo (hi,lo bf16 bit patterns)
__device__ __forceinline__ unsigned int bf16rne(float x) {
  unsigned int u = __float_as_uint(x);
  return (u + 0x7fffu + ((u >> 16) & 1u)) >> 16;
}
__device__ __forceinline__ void splitbf(float x, unsigned int& h, unsigned int& l) {
  h = bf16rne(x);
  float hf = __uint_as_float(h << 16);
  l = bf16rne(x - hf);
}
__device__ __forceinline__ unsigned int packbf(float v) {
  unsigned int h, lo;
  splitbf(v, h, lo);
  return h | (lo << 16);
}

// stable top-16 insertion (keeps lower index on ties when fed ascending j)
__device__ __forceinline__ void insert16(float d, int id, float* best, int* bidx) {
#pragma unroll
  for (int p = 0; p < KNB; ++p) {
    bool c = d < best[p];
    float tb = best[p]; int ti = bidx[p];
    best[p] = c ? d : tb; bidx[p] = c ? id : ti;
    d = c ? tb : d; id = c ? ti : id;
  }
}

// one bitonic compare-exchange pass over a 16-float register array.
// J,K are literal constants -> indices fold to constants, array stays in regs.
#define BPASS(arr, J, K) \
  _Pragma("unroll") \
  for (int i = 0; i < 16; ++i) { \
    int ix = i ^ (J); \
    if (ix > i) { \
      float lo = fminf(arr[i], arr[ix]); \
      float hi = fmaxf(arr[i], arr[ix]); \
      if ((i & (K)) == 0) { arr[i] = lo; arr[ix] = hi; } \
      else { arr[i] = hi; arr[ix] = lo; } \
    } \
  }

// exact reference distance chain (bit-replicates f32 expanded form)
__device__ __forceinline__ float qsq(float4 qv) {
  return __fadd_rn(__fadd_rn(__fmul_rn(qv.x, qv.x), __fmul_rn(qv.y, qv.y)),
                   __fmul_rn(qv.z, qv.z));
}
__device__ __forceinline__ float refdist(float4 qv, float sq, float4 rv) {
  float sr = qsq(rv);
  float dot = __fmaf_rn(qv.z, rv.z, __fmaf_rn(qv.y, rv.y, __fmul_rn(qv.x, rv.x)));
  return __fsub_rn(__fadd_rn(sq, sr), __fadd_rn(dot, dot));
}
__device__ __forceinline__ float refdist_sr(float4 qv, float sq, float4 rv) {
  float dot = __fmaf_rn(qv.z, rv.z, __fmaf_rn(qv.y, rv.y, __fmul_rn(qv.x, rv.x)));
  return __fsub_rn(__fadd_rn(sq, rv.w), __fadd_rn(dot, dot));
}

// ---------------- dtype autodetect ----------------
__global__ void k_detect(const void* __restrict__ pts1, int* __restrict__ flag) {
  int tid = threadIdx.x;  // 64
  const bf16* p = (const bf16*)pts1;
  int cnt = 0;
  for (int i = tid; i < 1024; i += 64) {
    float v = __bfloat162float(p[i]);
    if (!(fabsf(v) <= 64.f)) cnt++;
  }
#pragma unroll
  for (int s = 32; s; s >>= 1) cnt += __shfl_down(cnt, s);
  if (tid == 0) *flag = (cnt >= 8) ? 1 : 0;
}

// ---------------- prep ----------------
struct PrepTab {
  const void* src[40];
  int off[40];
  int n[40];
  float scale[40];
};

__global__ void k_prep(PrepTab tab, float* __restrict__ W, const int* __restrict__ flag) {
  int f32 = *flag;
  int a = blockIdx.x;
  const void* s = tab.src[a];
  float* d = W + tab.off[a];
  float sc = tab.scale[a];
  for (int i = threadIdx.x; i < tab.n[a]; i += blockDim.x) d[i] = ldin(s, i, f32) * sc;
}

// ---------------- MFMA weight fragment prep ----------------
// frag f: 64 lanes x {hi float4(8 bf16), lo float4}. B-layout: lane l holds
// W[srck(ks*32+(l>>4)*8+e)][nt*16+(l&15)], word r = elem2r | elem2r+1<<16.
// mode 0: srck = k (<kreal else 0). mode 1 (cw3a): A=[f2(64)|pd(3)|0]:
//   k<64 -> k+3; 64..66 -> k-64; else 0.
struct WTab { int woff[16]; int nn[16]; int kreal[16]; int mode[16]; int fb[16]; int nm; };

__global__ __launch_bounds__(64) void k_wbprep(WTab wt, const float* __restrict__ W,
                                               unsigned int* __restrict__ WB) {
  int f = blockIdx.x, l = threadIdx.x;
  int m = 0;
  for (int i = 1; i < wt.nm; ++i)
    if (wt.fb[i] <= f) m = i;
  int ntile = wt.nn[m] >> 4;
  int local = f - wt.fb[m];
  int ks = local / ntile, nt = local - ks * ntile;
  int g = l >> 4, c = l & 15;
  int col = nt * 16 + c;
  int N = wt.nn[m], kr = wt.kreal[m], wo = wt.woff[m], mode = wt.mode[m];
  unsigned int hw[4], lw[4];
#pragma unroll
  for (int r = 0; r < 4; ++r) {
    float wv2[2];
#pragma unroll
    for (int e = 0; e < 2; ++e) {
      int k = ks * 32 + g * 8 + 2 * r + e;
      int srck;
      if (mode == 1) srck = (k < 64) ? k + 3 : ((k < 67) ? k - 64 : -1);
      else srck = (k < kr) ? k : -1;
      wv2[e] = (srck >= 0) ? W[wo + srck * N + col] : 0.f;
    }
    unsigned int h0, l0, h1, l1;
    splitbf(wv2[0], h0, l0);
    splitbf(wv2[1], h1, l1);
    hw[r] = h0 | (h1 << 16);
    lw[r] = l0 | (l1 << 16);
  }
  unsigned int* d = WB + ((size_t)f * 64 + l) * 8;
  d[0] = hw[0]; d[1] = hw[1]; d[2] = hw[2]; d[3] = hw[3];
  d[4] = lw[0]; d[5] = lw[1]; d[6] = lw[2]; d[7] = lw[3];
}

// ---------------- pack (w = qsq, bit-identical chain to the old tile staging) --
__global__ void k_pack(const void* __restrict__ xyz1, const void* __restrict__ xyz2,
                       const void* __restrict__ xyz2w, const void* __restrict__ sf,
                       float4* __restrict__ pk, const int* __restrict__ flag) {
  int f32 = *flag;
  int t = blockIdx.x * 256 + threadIdx.x;  // B*N
  int b = t >> 13, n = t & (NPTS - 1);
  size_t base = (size_t)b * 3 * NPTS + n;
  float ax = ldin(xyz1, base, f32), ay = ldin(xyz1, base + NPTS, f32), az = ldin(xyz1, base + 2 * NPTS, f32);
  float sx = ldin(sf, base, f32),   sy = ldin(sf, base + NPTS, f32),   sz = ldin(sf, base + 2 * NPTS, f32);
  float4 p0 = make_float4(__fadd_rn(ax, sx), __fadd_rn(ay, sy), __fadd_rn(az, sz), 0.f);
  p0.w = qsq(p0);
  float4 p1 = make_float4(ax, ay, az, 0.f);
  p1.w = qsq(p1);
  float4 p2 = make_float4(ldin(xyz2, base, f32), ldin(xyz2, base + NPTS, f32), ldin(xyz2, base + 2 * NPTS, f32), 0.f);
  p2.w = qsq(p2);
  float4 p3 = make_float4(ldin(xyz2w, base, f32), ldin(xyz2w, base + NPTS, f32), ldin(xyz2w, base + 2 * NPTS, f32), 0.f);
  p3.w = qsq(p3);
  pk[t]          = p0;
  pk[t + BN]     = p1;
  pk[t + 2 * BN] = p2;
  pk[t + 3 * BN] = p3;
}

// ---------------- transpose (writes packed hi|lo u32) ----------------
__global__ __launch_bounds__(64) void k_tr(const void* __restrict__ src,
                                           unsigned int* __restrict__ dst,
                                           const int* __restrict__ flag) {
  __shared__ float tile[64][65];
  int f32 = *flag;
  int tid = threadIdx.x;
  int n0 = blockIdx.x * 64;
  int b = blockIdx.y;
  for (int i = 0; i < 64; ++i)
    tile[i][tid] = ldin(src, ((size_t)b * 64 + i) * NPTS + n0 + tid, f32);
  __syncthreads();
  for (int i = 0; i < 64; ++i)
    dst[((size_t)b * NPTS + n0 + i) * 64 + tid] = packbf(tile[tid][i]);
}

// ---------------- KNN partials: scalar-broadcast ref reads (no LDS tile) -----
// Ref addresses depend only on blockIdx + unrolled counters -> wave-uniform ->
// compiler emits s_load into SGPRs (SMEM pipe; frees the LDS 12cyc/b128 pipe).
// pk.w carries qsq (set in k_pack with the identical chain) -> refdist_sr
// values are bit-identical to the staged-tile version. Selection logic,
// capture order, and post are unchanged -> bit-identical indices.
__global__ __launch_bounds__(256) void k_knnp(const float4* __restrict__ pk,
                                              unsigned short* __restrict__ part_idx) {
  __shared__ unsigned short sbuf[256 * CAP];
  int tid = threadIdx.x;
  int n = blockIdx.x * 256 + tid;
  int b = blockIdx.y;
  int which = blockIdx.z >> 4;   // NPART==16
  int part  = blockIdx.z & 15;
  const float4* q = pk + (size_t)which * BN;
  const float4* r = pk + (size_t)(2 + which) * BN + (size_t)b * NPTS;
  float4 qv = q[b * NPTS + n];
  float sq = qsq(qv);

  float best[KNB];
#pragma unroll
  for (int p = 0; p < KNB; ++p) best[p] = 3.4e38f;   // sorted asc (all equal)

  const int c0 = part * PARTC;
  // pass 1: exact 16 smallest distance VALUES (batched bitonic)
  for (int t = 0; t < PARTC / 16; ++t) {
    const float4* rr = r + c0 + t * 16;   // uniform across the wave
    float fr[16];
#pragma unroll
    for (int j = 0; j < 16; ++j) fr[j] = refdist_sr(qv, sq, rr[j]);
    // bitonic sort fr ascending (10 passes)
    BPASS(fr, 1, 2)
    BPASS(fr, 2, 4) BPASS(fr, 1, 4)
    BPASS(fr, 4, 8) BPASS(fr, 2, 8) BPASS(fr, 1, 8)
    BPASS(fr, 8, 16) BPASS(fr, 4, 16) BPASS(fr, 2, 16) BPASS(fr, 1, 16)
    // min-merge: keep 16 smallest of best(asc) U fr(asc) -> bitonic in best
#pragma unroll
    for (int i = 0; i < 16; ++i) best[i] = fminf(best[i], fr[15 - i]);
    // bitonic cleanup -> best sorted asc again (K=16: all-ascending passes)
    BPASS(best, 8, 16) BPASS(best, 4, 16) BPASS(best, 2, 16) BPASS(best, 1, 16)
  }
  float thr = best[KNB - 1];

  // pass 2: capture candidate indices with dd <= thr (ascending global index)
  int cnt = 0;
  for (int t = 0; t < PARTC / 16; ++t) {
    const float4* rr = r + c0 + t * 16;   // uniform across the wave
#pragma unroll
    for (int j = 0; j < 16; ++j) {
      float dd = refdist_sr(qv, sq, rr[j]);
      if (dd <= thr && cnt < CAP) {
        sbuf[tid * CAP + cnt] = (unsigned short)(c0 + t * 16 + j);
        cnt++;
      }
    }
  }

  // post: exact (d, idx) selection among <=CAP captured
  float bd[KNB]; int bi[KNB];
#pragma unroll
  for (int p = 0; p < KNB; ++p) { bd[p] = 3.4e38f; bi[p] = 0; }
  for (int m = 0; m < CAP; ++m) {
    if (m < cnt) {
      int id = sbuf[tid * CAP + m];
      float dd = refdist(qv, sq, r[id]);
      insert16(dd, id, bd, bi);
    }
  }
  size_t o = ((((size_t)which * BATCH + b) * NPART + part) * NPTS + n) * KNB;
#pragma unroll
  for (int p = 0; p < KNB; ++p) part_idx[o + p] = (unsigned short)bi[p];
}

// ---------------- KNN merge (16 parts x 16 u16 candidates, ascending feed) ----
__global__ void k_merge(const float4* __restrict__ pk,
                        const unsigned short* __restrict__ part_idx,
                        int* __restrict__ idxf) {
  int t = blockIdx.x * 256 + threadIdx.x;  // (which*B+b)*N+n
  int n = t & (NPTS - 1);
  int wb = t >> 13;
  int b = wb & (BATCH - 1);
  int which = wb / BATCH;
  const float4* q = pk + (size_t)which * BN;
  const float4* r = pk + (size_t)(2 + which) * BN + (size_t)b * NPTS;
  float4 qv = q[b * NPTS + n];
  float sq = qsq(qv);
  float best[KNB]; int bidx[KNB];
#pragma unroll
  for (int p = 0; p < KNB; ++p) { best[p] = 3.4e38f; bidx[p] = 0; }
  for (int part = 0; part < NPART; ++part) {
    size_t o = ((((size_t)which * BATCH + b) * NPART + part) * NPTS + n) * KNB;
#pragma unroll
    for (int m = 0; m < KNB; ++m) {
      int id = part_idx[o + m];
      float dd = refdist(qv, sq, r[id]);
      if (dd < best[KNB - 1]) insert16(dd, id, best, bidx);
    }
  }
  size_t oo = (size_t)t * KNB;
#pragma unroll
  for (int p = 0; p < KNB; ++p) idxf[oo + p] = bidx[p];
}

// ---------------- MFMA helpers ----------------
__device__ __forceinline__ bf16x8 mk8(unsigned int w0, unsigned int w1,
                                      unsigned int w2, unsigned int w3) {
  u32x4 u;
  u.x = w0; u.y = w1; u.z = w2; u.w = w3;
  return __builtin_bit_cast(bf16x8, u);
}

// build A hi/lo frags from 8 packed (hi|lo<<16) u32
__device__ __forceinline__ void mkA_pk(u32x4 qa, u32x4 qb, bf16x8& ah, bf16x8& al) {
  unsigned int q0 = qa.x, q1 = qa.y, q2 = qa.z, q3 = qa.w;
  unsigned int q4 = qb.x, q5 = qb.y, q6 = qb.z, q7 = qb.w;
  ah = mk8((q0 & 0xffffu) | (q1 << 16), (q2 & 0xffffu) | (q3 << 16),
           (q4 & 0xffffu) | (q5 << 16), (q6 & 0xffffu) | (q7 << 16));
  al = mk8((q0 >> 16) | (q1 & 0xffff0000u), (q2 >> 16) | (q3 & 0xffff0000u),
           (q4 >> 16) | (q5 & 0xffff0000u), (q6 >> 16) | (q7 & 0xffff0000u));
}
__device__ __forceinline__ void mkA_lds(const unsigned int* p, bf16x8& ah, bf16x8& al) {
  mkA_pk(*(const u32x4*)p, *(const u32x4*)(p + 4), ah, al);
}

#define FRAG_IEW2 0
#define FRAG_PECW 8
#define FRAG_PMW1 12
#define FRAG_PMW2 20
#define FRAG_PMW3 28
#define FRAG_C1A  32
#define FRAG_C1B  48
#define FRAG_C2A  56
#define FRAG_C2B  72
#define FRAG_C3A  80
#define FRAG_C3B  92
#define FRAG_C4A  100
#define FRAG_C4B  116
#define NFRAG     124

// acc += A * Wfrag with split-bf16 3-product emulation
__device__ __forceinline__ f32x4 mfma_bb(bf16x8 ah, bf16x8 al,
                                         const unsigned int* __restrict__ WB,
                                         int f, int lane, f32x4 acc) {
  const u32x4* p = (const u32x4*)WB + ((size_t)(f * 64 + lane)) * 2;
  u32x4 h4 = p[0], l4 = p[1];
  bf16x8 bh = __builtin_bit_cast(bf16x8, h4);
  bf16x8 bl = __builtin_bit_cast(bf16x8, l4);
  acc = __builtin_amdgcn_mfma_f32_16x16x32_bf16(al, bh, acc, 0, 0, 0);
  acc = __builtin_amdgcn_mfma_f32_16x16x32_bf16(ah, bl, acc, 0, 0, 0);
  acc = __builtin_amdgcn_mfma_f32_16x16x32_bf16(ah, bh, acc, 0, 0, 0);
  return acc;
}

// one 64->64 layer: A from xp (sample row = lane&15), 2 k-steps x 4 n-tiles
__device__ __forceinline__ void layer64(const unsigned int* __restrict__ xp,
                                        const unsigned int* __restrict__ WB,
                                        int fbase, int lane, f32x4 acc[4]) {
  int c = lane & 15, g = lane >> 4;
  bf16x8 ah0, al0, ah1, al1;
  mkA_lds(xp + c * 68 + g * 8, ah0, al0);
  mkA_lds(xp + c * 68 + 32 + g * 8, ah1, al1);
#pragma unroll
  for (int nt = 0; nt < 4; ++nt) {
    acc[nt] = mfma_bb(ah0, al0, WB, fbase + nt, lane, acc[nt]);
    acc[nt] = mfma_bb(ah1, al1, WB, fbase + 4 + nt, lane, acc[nt]);
  }
}

// epilogue: optional bn(+relu), split to bf16 hi/lo, pack, write to xp
__device__ __forceinline__ void epi_pack(int lane, f32x4 acc[4], unsigned int* xp,
                                         const float* gw, const float* bw, bool relu) {
  int c = lane & 15, g = lane >> 4;
#pragma unroll
  for (int nt = 0; nt < 4; ++nt) {
    float gv = gw ? gw[nt * 16 + c] : 1.f;
    float bv = gw ? bw[nt * 16 + c] : 0.f;
#pragma unroll
    for (int r = 0; r < 4; ++r) {
      float v = acc[nt][r];
      if (gw) v = fmaf(v, gv, bv);
      if (relu) v = fmaxf(v, 0.f);
      xp[(g * 4 + r) * 68 + nt * 16 + c] = packbf(v);
    }
  }
}

// epilogue with leaky relu (k_feat chains)
__device__ __forceinline__ void epi_lrelu(int lane, f32x4 acc[4], unsigned int* xp) {
  int c = lane & 15, g = lane >> 4;
#pragma unroll
  for (int nt = 0; nt < 4; ++nt) {
#pragma unroll
    for (int r = 0; r < 4; ++r)
      xp[(g * 4 + r) * 68 + nt * 16 + c] = packbf(lrelu(acc[nt][r]));
  }
}

// ---------------- k_logit: IPC MLP on matrix cores (split-bf16), softmax ------
__global__ __launch_bounds__(256, 3) void k_logit(const float* __restrict__ W,
                                                  const unsigned int* __restrict__ WB,
                                                  const int* __restrict__ idxf,
                                                  const float4* __restrict__ pk,
                                                  unsigned short* __restrict__ AW) {
  __shared__ unsigned int xp_s[4][16 * 68];  // packed hi|lo activations per sample
  __shared__ unsigned int tg_s[4][16 * 36];  // packed trig rows (24 real + 8 zero)
  const int l = threadIdx.x & 63;
  const int wv = threadIdx.x >> 6;
  const int c = l & 15, g = l >> 4;
  unsigned int* xp = xp_s[wv];
  unsigned int* tg = tg_s[wv];
  const int which = blockIdx.y;
  const int pt = blockIdx.x * 4 + wv;    // b*N+n
  const int n = pt & (NPTS - 1);
  const int b = pt >> 13;

  int idxv = idxf[(((size_t)which * BATCH + b) * NPTS + n) * KNB + c];
  float4 pv = pk[(size_t)2 * BN + (size_t)b * NPTS + idxv];  // x2[idx]
  float4 qp = pk[(size_t)BN + pt];                           // x1[n]
  float pdx = pv.x - qp.x, pdy = pv.y - qp.y, pdz = pv.z - qp.z;

  // ---- trig: 12 sincos per sample, 3 per k-group lane ----
  {
    unsigned int* tr = tg + c * 36;
#pragma unroll
    for (int j = 0; j < 3; ++j) {
      int t = g * 3 + j;
      int c3 = t >> 2, fq = t & 3;
      float pdc = (c3 == 0) ? pdx : (c3 == 1) ? pdy : pdz;
      float pe = (pdc - rintf(pdc * 4.f) * 0.25f) * 4.f;
      float tt = pe / 1.000001f * 6.28318530717958647692f;
      float dv = (fq == 0) ? 1.f : (fq == 1) ? 10.f : (fq == 2) ? 100.f : 1000.f;
      float sn, cs;
      sincosf(tt / dv, &sn, &cs);
      unsigned int hs, ls2, hc, lc;
      splitbf(sn, hs, ls2);
      splitbf(cs, hc, lc);
      tr[2 * t] = hs | (ls2 << 16);
      tr[2 * t + 1] = hc | (lc << 16);
    }
    if (g == 3) {
#pragma unroll
      for (int z = 24; z < 32; ++z) tr[z] = 0u;
    }
  }

  // ---- ie1: 3->64, bn, relu (exact f32), pack to xp[sample=c][ch] ----
  {
    unsigned int* xr = xp + c * 68 + g * 16;
#pragma unroll
    for (int m4 = 0; m4 < 4; ++m4) {
      int ch = g * 16 + m4 * 4;
      float4 bb = *(const float4*)(W + WOFF_IEB1 + ch);
      float4 w0 = *(const float4*)(W + WOFF_IEW1 + ch);
      float4 w1 = *(const float4*)(W + WOFF_IEW1 + 64 + ch);
      float4 w2 = *(const float4*)(W + WOFF_IEW1 + 128 + ch);
      float4 gg = *(const float4*)(W + WOFF_IEG + ch);
      float4 bt = *(const float4*)(W + WOFF_IEBT + ch);
      float v0 = fmaf(pdz, w2.x, fmaf(pdy, w1.x, fmaf(pdx, w0.x, bb.x)));
      float v1 = fmaf(pdz, w2.y, fmaf(pdy, w1.y, fmaf(pdx, w0.y, bb.y)));
      float v2 = fmaf(pdz, w2.z, fmaf(pdy, w1.z, fmaf(pdx, w0.z, bb.z)));
      float v3 = fmaf(pdz, w2.w, fmaf(pdy, w1.w, fmaf(pdx, w0.w, bb.w)));
      v0 = fmaxf(fmaf(v0, gg.x, bt.x), 0.f);
      v1 = fmaxf(fmaf(v1, gg.y, bt.y), 0.f);
      v2 = fmaxf(fmaf(v2, gg.z, bt.z), 0.f);
      v3 = fmaxf(fmaf(v3, gg.w, bt.w), 0.f);
      u32x4 pk4;
      pk4.x = packbf(v0); pk4.y = packbf(v1);
      pk4.z = packbf(v2); pk4.w = packbf(v3);
      *(u32x4*)(xr + m4 * 4) = pk4;
    }
  }
  __builtin_amdgcn_wave_barrier();

  f32x4 acc[4];
  // ---- ie2 + pec (accumulated into one f32 acc; init = ie_b2 + pec_b) ----
#pragma unroll
  for (int nt = 0; nt < 4; ++nt) {
    float bs = W[WOFF_IEB2 + nt * 16 + c] + W[WOFF_PECB + nt * 16 + c];
    acc[nt].x = bs; acc[nt].y = bs; acc[nt].z = bs; acc[nt].w = bs;
  }
  layer64(xp, WB, FRAG_IEW2, l, acc);
  {
    bf16x8 ah, al;
    mkA_lds(tg + c * 36 + g * 8, ah, al);
#pragma unroll
    for (int nt = 0; nt < 4; ++nt)
      acc[nt] = mfma_bb(ah, al, WB, FRAG_PECW + nt, l, acc[nt]);
  }
  __builtin_amdgcn_wave_barrier();
  epi_pack(l, acc, xp, nullptr, nullptr, false);
  __builtin_amdgcn_wave_barrier();

  // ---- pm1: 64->64, bn, relu ----
#pragma unroll
  for (int nt = 0; nt < 4; ++nt) {
    float bs = W[WOFF_PMB1 + nt * 16 + c];
    acc[nt].x = bs; acc[nt].y = bs; acc[nt].z = bs; acc[nt].w = bs;
  }
  layer64(xp, WB, FRAG_PMW1, l, acc);
  __builtin_amdgcn_wave_barrier();
  epi_pack(l, acc, xp, W + WOFF_PMG1, W + WOFF_PMT1, true);
  __builtin_amdgcn_wave_barrier();

  // ---- pm2: 64->64, bn, relu ----
#pragma unroll
  for (int nt = 0; nt < 4; ++nt) {
    float bs = W[WOFF_PMB2 + nt * 16 + c];
    acc[nt].x = bs; acc[nt].y = bs; acc[nt].z = bs; acc[nt].w = bs;
  }
  layer64(xp, WB, FRAG_PMW2, l, acc);
  __builtin_amdgcn_wave_barrier();
  epi_pack(l, acc, xp, W + WOFF_PMG2, W + WOFF_PMT2, true);
  __builtin_amdgcn_wave_barrier();

  // ---- pm3: 64->32, bn (no relu), stays in regs ----
  f32x4 a3[2];
#pragma unroll
  for (int nt = 0; nt < 2; ++nt) {
    float bs = W[WOFF_PMB3 + nt * 16 + c];
    a3[nt].x = bs; a3[nt].y = bs; a3[nt].z = bs; a3[nt].w = bs;
  }
  {
    bf16x8 ah0, al0, ah1, al1;
    mkA_lds(xp + c * 68 + g * 8, ah0, al0);
    mkA_lds(xp + c * 68 + 32 + g * 8, ah1, al1);
#pragma unroll
    for (int nt = 0; nt < 2; ++nt) {
      a3[nt] = mfma_bb(ah0, al0, WB, FRAG_PMW3 + nt, l, a3[nt]);
      a3[nt] = mfma_bb(ah1, al1, WB, FRAG_PMW3 + 2 + nt, l, a3[nt]);
    }
  }
#pragma unroll
  for (int nt = 0; nt < 2; ++nt) {
    float gv = W[WOFF_PMG3 + nt * 16 + c];
    float bv = W[WOFF_PMT3 + nt * 16 + c];
#pragma unroll
    for (int r = 0; r < 4; ++r) a3[nt][r] = fmaf(a3[nt][r], gv, bv);
  }

  // ---- pm4 dot (per-lane 2-ch partial, 16-lane butterfly) + bn ----
  float w4a = W[WOFF_PMW4 + c];
  float w4b = W[WOFF_PMW4 + 16 + c];
  f32x4 pr;
#pragma unroll
  for (int r = 0; r < 4; ++r) pr[r] = fmaf(a3[1][r], w4b, a3[0][r] * w4a);
#pragma unroll
  for (int s = 1; s < 16; s <<= 1) {
#pragma unroll
    for (int r = 0; r < 4; ++r) pr[r] += __shfl_xor(pr[r], s);
  }
  float b4 = W[WOFF_PMB4], g4 = W[WOFF_PMG4], t4 = W[WOFF_PMT4];
  f32x4 lg;
#pragma unroll
  for (int r = 0; r < 4; ++r) lg[r] = fmaf(pr[r] + b4, g4, t4);

  // ---- softmax over 16 neighbors (samples): group g holds samples 4g+r ----
  float m = fmaxf(fmaxf(lg[0], lg[1]), fmaxf(lg[2], lg[3]));
#pragma unroll
  for (int s = 16; s < 64; s <<= 1) m = fmaxf(m, __shfl_xor(m, s));
  f32x4 e;
  float ssum = 0.f;
#pragma unroll
  for (int r = 0; r < 4; ++r) { e[r] = expf(lg[r] - m); ssum += e[r]; }
#pragma unroll
  for (int s = 16; s < 64; s <<= 1) ssum += __shfl_xor(ssum, s);
  if (c < 4) {
    int k = g * 4 + c;
    float ev = (c == 0) ? e[0] : (c == 1) ? e[1] : (c == 2) ? e[2] : e[3];
    float aw = ev / ssum;
    AW[(((size_t)which * BATCH + b) * NPTS + n) * KNB + k] =
        (unsigned short)__float2uint_rn(aw * 65535.f);
  }
}

// ---------------- k_feat: chains on matrix cores (split-bf16) ----------------
// block = 4 waves = 4 points; wave = one point's 16 neighbors (16-sample batch).
__global__ __launch_bounds__(256, 3) void k_feat(const unsigned int* __restrict__ P1T,
                                                 const unsigned int* __restrict__ P2T,
                                                 const float* __restrict__ W,
                                                 const unsigned int* __restrict__ WB,
                                                 const int* __restrict__ idxf,
                                                 const unsigned short* __restrict__ AW,
                                                 const float4* __restrict__ pk,
                                                 void* __restrict__ out,
                                                 const int* __restrict__ flag) {
  __shared__ unsigned int xp_s[4][16 * 68];
  __shared__ unsigned int costb[4][132];   // [point][costA(64)|costB(64)] packed
  __shared__ unsigned int u4b[4][68];      // chain4 mid activations [point][64]
  __shared__ float awb[4][16];
  const int l = threadIdx.x & 63;
  const int wv = threadIdx.x >> 6;
  const int c = l & 15, g = l >> 4;
  unsigned int* xp = xp_s[wv];
  const int f32 = *flag;
  const int pt = blockIdx.x * 4 + wv;    // b*N+n
  const int n = pt & (NPTS - 1);
  const int b = pt >> 13;
  float4 qp = pk[(size_t)BN + pt];       // x1[n]
  u32x4 z4;
  z4.x = 0u; z4.y = 0u; z4.z = 0u; z4.w = 0u;

  // gp1 fragments (layer-a k-steps 0,1): row n broadcast
  bf16x8 p1h[2], p1l[2];
  {
    const unsigned int* pr = P1T + ((size_t)b * NPTS + n) * 64;
#pragma unroll
    for (int ks = 0; ks < 2; ++ks) {
      u32x4 qa = *(const u32x4*)(pr + ks * 32 + g * 8);
      u32x4 qb = *(const u32x4*)(pr + ks * 32 + g * 8 + 4);
      mkA_pk(qa, qb, p1h[ks], p1l[ks]);
    }
  }

  for (int which = 0; which < 2; ++which) {
    int idxv = idxf[(((size_t)which * BATCH + b) * NPTS + n) * KNB + c];
    float4 pv = pk[(size_t)2 * BN + (size_t)b * NPTS + idxv];  // x2[idx]
    float pdx = pv.x - qp.x, pdy = pv.y - qp.y, pdz = pv.z - qp.z;
    float aw = (float)AW[(((size_t)which * BATCH + b) * NPTS + n) * KNB + c] *
               (1.f / 65535.f);
    if (g == 0) awb[wv][c] = aw;

    // gp2 fragments (layer-a k-steps 2,3): per-sample row idxv
    bf16x8 p2h[2], p2l[2];
    {
      const unsigned int* qr = P2T + ((size_t)b * NPTS + idxv) * 64;
#pragma unroll
      for (int ks = 0; ks < 2; ++ks) {
        u32x4 qa = *(const u32x4*)(qr + ks * 32 + g * 8);
        u32x4 qb = *(const u32x4*)(qr + ks * 32 + g * 8 + 4);
        mkA_pk(qa, qb, p2h[ks], p2l[ks]);
      }
    }

    // ---- layer a: [gp1|gp2](128) -> 64 ----
    f32x4 acc[4];
    {
      const float* Ba = W + (which == 0 ? WOFF_CB1A : WOFF_CB2A);
      int fa = (which == 0) ? FRAG_C1A : FRAG_C2A;
#pragma unroll
      for (int nt = 0; nt < 4; ++nt) {
        float bs = Ba[nt * 16 + c];
        acc[nt].x = bs; acc[nt].y = bs; acc[nt].z = bs; acc[nt].w = bs;
      }
#pragma unroll
      for (int nt = 0; nt < 4; ++nt) {
        acc[nt] = mfma_bb(p1h[0], p1l[0], WB, fa + nt, l, acc[nt]);
        acc[nt] = mfma_bb(p1h[1], p1l[1], WB, fa + 4 + nt, l, acc[nt]);
        acc[nt] = mfma_bb(p2h[0], p2l[0], WB, fa + 8 + nt, l, acc[nt]);
        acc[nt] = mfma_bb(p2h[1], p2l[1], WB, fa + 12 + nt, l, acc[nt]);
      }
    }
    __builtin_amdgcn_wave_barrier();
    epi_lrelu(l, acc, xp);
    __builtin_amdgcn_wave_barrier();

    // ---- layer b: 64 -> 64 ----
    {
      const float* Bb = W + (which == 0 ? WOFF_CB1B : WOFF_CB2B);
      int fb = (which == 0) ? FRAG_C1B : FRAG_C2B;
      bf16x8 ah0, al0, ah1, al1;
      mkA_lds(xp + c * 68 + g * 8, ah0, al0);
      mkA_lds(xp + c * 68 + 32 + g * 8, ah1, al1);
#pragma unroll
      for (int nt = 0; nt < 4; ++nt) {
        float bs = Bb[nt * 16 + c];
        acc[nt].x = bs; acc[nt].y = bs; acc[nt].z = bs; acc[nt].w = bs;
        acc[nt] = mfma_bb(ah0, al0, WB, fb + nt, l, acc[nt]);
        acc[nt] = mfma_bb(ah1, al1, WB, fb + 4 + nt, l, acc[nt]);
      }
    }
    __builtin_amdgcn_wave_barrier();

    if (which == 1) {
      // ---- cw3a: A = [lrelu(f2)(cols 0..63) | pd(64..66) | 0] (weights permuted) ----
      epi_lrelu(l, acc, xp);
      if (g == 0) {
        xp[c * 68 + 64] = packbf(pdx);
        xp[c * 68 + 65] = packbf(pdy);
        xp[c * 68 + 66] = packbf(pdz);
        xp[c * 68 + 67] = 0u;
      }
      __builtin_amdgcn_wave_barrier();
      {
        bf16x8 ah0, al0, ah1, al1, ah2, al2;
        mkA_lds(xp + c * 68 + g * 8, ah0, al0);
        mkA_lds(xp + c * 68 + 32 + g * 8, ah1, al1);
        u32x4 qa3 = z4;
        if (g == 0) qa3 = *(const u32x4*)(xp + c * 68 + 64);
        mkA_pk(qa3, z4, ah2, al2);
#pragma unroll
        for (int nt = 0; nt < 4; ++nt) {
          float bs = W[WOFF_CB3A + nt * 16 + c];
          acc[nt].x = bs; acc[nt].y = bs; acc[nt].z = bs; acc[nt].w = bs;
          acc[nt] = mfma_bb(ah0, al0, WB, FRAG_C3A + nt, l, acc[nt]);
          acc[nt] = mfma_bb(ah1, al1, WB, FRAG_C3A + 4 + nt, l, acc[nt]);
          acc[nt] = mfma_bb(ah2, al2, WB, FRAG_C3A + 8 + nt, l, acc[nt]);
        }
      }
      __builtin_amdgcn_wave_barrier();
      epi_lrelu(l, acc, xp);
      __builtin_amdgcn_wave_barrier();
      // ---- cw3b: 64 -> 64 ----
      {
        bf16x8 ah0, al0, ah1, al1;
        mkA_lds(xp + c * 68 + g * 8, ah0, al0);
        mkA_lds(xp + c * 68 + 32 + g * 8, ah1, al1);
#pragma unroll
        for (int nt = 0; nt < 4; ++nt) {
          float bs = W[WOFF_CB3B + nt * 16 + c];
          acc[nt].x = bs; acc[nt].y = bs; acc[nt].z = bs; acc[nt].w = bs;
          acc[nt] = mfma_bb(ah0, al0, WB, FRAG_C3B + nt, l, acc[nt]);
          acc[nt] = mfma_bb(ah1, al1, WB, FRAG_C3B + 4 + nt, l, acc[nt]);
        }
      }
      __builtin_amdgcn_wave_barrier();
    }

    // ---- weighted sum over 16 neighbors -> cost row, stage to costb ----
    {
      float4 a4r = *(const float4*)&awb[wv][g * 4];
#pragma unroll
      for (int nt = 0; nt < 4; ++nt) {
        float s = lrelu(acc[nt][0]) * a4r.x;
        s = fmaf(lrelu(acc[nt][1]), a4r.y, s);
        s = fmaf(lrelu(acc[nt][2]), a4r.z, s);
        s = fmaf(lrelu(acc[nt][3]), a4r.w, s);
        s += __shfl_xor(s, 16);
        s += __shfl_xor(s, 32);
        if (g == 0) costb[wv][which * 64 + nt * 16 + c] = packbf(s);
      }
    }
  }
  __syncthreads();

  // ---- chain4 layer a: batch-4 points (A rows 0..3), n-tile = wv ----
  f32x4 a4;
  {
    float bs = W[WOFF_CB4A + wv * 16 + c];
    a4.x = bs; a4.y = bs; a4.z = bs; a4.w = bs;
#pragma unroll
    for (int ks = 0; ks < 4; ++ks) {
      u32x4 qa = z4, qb = z4;
      if (c < 4) {
        qa = *(const u32x4*)(&costb[c][ks * 32 + g * 8]);
        qb = *(const u32x4*)(&costb[c][ks * 32 + g * 8 + 4]);
      }
      bf16x8 ah, al;
      mkA_pk(qa, qb, ah, al);
      a4 = mfma_bb(ah, al, WB, FRAG_C4A + ks * 4 + wv, l, a4);
    }
  }
  if (g == 0) {
#pragma unroll
    for (int r = 0; r < 4; ++r) u4b[r][wv * 16 + c] = packbf(lrelu(a4[r]));
  }
  __syncthreads();

  // ---- chain4 layer b + output ----
  {
    float bs = W[WOFF_CB4B + wv * 16 + c];
    a4.x = bs; a4.y = bs; a4.z = bs; a4.w = bs;
#pragma unroll
    for (int ks = 0; ks < 2; ++ks) {
      u32x4 qa = z4, qb = z4;
      if (c < 4) {
        qa = *(const u32x4*)(&u4b[c][ks * 32 + g * 8]);
        qb = *(const u32x4*)(&u4b[c][ks * 32 + g * 8 + 4]);
      }
      bf16x8 ah, al;
      mkA_pk(qa, qb, ah, al);
      a4 = mfma_bb(ah, al, WB, FRAG_C4B + ks * 4 + wv, l, a4);
    }
  }
  if (g == 0) {
    int n0 = (blockIdx.x * 4) & (NPTS - 1);
    int b0 = (blockIdx.x * 4) >> 13;
    size_t ob = (size_t)b0 * 64 * NPTS + (size_t)(wv * 16 + c) * NPTS + n0;
#pragma unroll
    for (int r = 0; r < 4; ++r) stout(out, ob + r, lrelu(a4[r]), f32);
  }
}

// ---------------- host ----------------
extern "C" void kernel_launch(void* const* d_in, const int* in_sizes, int n_in,
                              void* d_out, int out_size, void* d_ws, size_t ws_size,
                              hipStream_t stream) {
  (void)in_sizes; (void)n_in; (void)out_size; (void)ws_size;
  float*  W    = (float*)d_ws;
  int*    FLAG = (int*)((char*)d_ws + BOFF_FLAG);
  float4* PK   = (float4*)((char*)d_ws + BOFF_PK);
  unsigned int* WBu = (unsigned int*)((char*)d_ws + BOFF_WB);
  int*    IDX  = (int*)((char*)d_ws + BOFF_IDX);
  unsigned short* AW = (unsigned short*)((char*)d_ws + BOFF_AW);
  unsigned int* P1T = (unsigned int*)((char*)d_ws + BOFF_P1T);
  unsigned int* P2T = (unsigned int*)((char*)d_ws + BOFF_P2T);
  unsigned short* PART = (unsigned short*)((char*)d_ws + BOFF_PART);

  static const int WOFFS[40] = {
    WOFF_CW1A, WOFF_CB1A, WOFF_CW1B, WOFF_CB1B,
    WOFF_CW2A, WOFF_CB2A, WOFF_CW2B, WOFF_CB2B,
    WOFF_CW3A, WOFF_CB3A, WOFF_CW3B, WOFF_CB3B,
    WOFF_CW4A, WOFF_CB4A, WOFF_CW4B, WOFF_CB4B,
    WOFF_IEW1, WOFF_IEB1, WOFF_IEG,  WOFF_IEBT,
    WOFF_IEW2, WOFF_IEB2, WOFF_PECW, WOFF_PECB,
    WOFF_PMW1, WOFF_PMB1, WOFF_PMG1, WOFF_PMT1,
    WOFF_PMW2, WOFF_PMB2, WOFF_PMG2, WOFF_PMT2,
    WOFF_PMW3, WOFF_PMB3, WOFF_PMG3, WOFF_PMT3,
    WOFF_PMW4, WOFF_PMB4, WOFF_PMG4, WOFF_PMT4};
  static const int WNS[40] = {
    8192, 64, 4096, 64,  8192, 64, 4096, 64,  4288, 64, 4096, 64,
    8192, 64, 4096, 64,  192, 64, 64, 64,  4096, 64,  1536, 64,
    4096, 64, 64, 64,  4096, 64, 64, 64,  2048, 32, 32, 32,  32, 1, 1, 1};

  PrepTab tab;
  for (int a = 0; a < 40; ++a) {
    tab.src[a] = d_in[6 + a];
    tab.off[a] = WOFFS[a];
    tab.n[a] = WNS[a];
    tab.scale[a] = 1.f;
  }
  tab.scale[18] = C_IE;                               // ie_g
  tab.scale[26] = C_PM; tab.scale[30] = C_PM;         // pm_g1, pm_g2
  tab.scale[34] = C_PM; tab.scale[38] = C_PM;         // pm_g3, pm_g4

  // fragment table: frag f = fb[m] + ks*(N/16) + nt
  WTab wt;
  {
    int f = 0, m = 0;
    auto add = [&](int woff, int N, int nks, int kreal, int mode) {
      wt.woff[m] = woff; wt.nn[m] = N; wt.kreal[m] = kreal;
      wt.mode[m] = mode; wt.fb[m] = f;
      f += nks * (N / 16); ++m;
    };
    add(WOFF_IEW2, 64, 2, 64, 0);    // 0..7
    add(WOFF_PECW, 64, 1, 24, 0);    // 8..11
    add(WOFF_PMW1, 64, 2, 64, 0);    // 12..19
    add(WOFF_PMW2, 64, 2, 64, 0);    // 20..27
    add(WOFF_PMW3, 32, 2, 64, 0);    // 28..31
    add(WOFF_CW1A, 64, 4, 128, 0);   // 32..47
    add(WOFF_CW1B, 64, 2, 64, 0);    // 48..55
    add(WOFF_CW2A, 64, 4, 128, 0);   // 56..71
    add(WOFF_CW2B, 64, 2, 64, 0);    // 72..79
    add(WOFF_CW3A, 64, 3, 67, 1);    // 80..91 (row-permuted [f2|pd|0])
    add(WOFF_CW3B, 64, 2, 64, 0);    // 92..99
    add(WOFF_CW4A, 64, 4, 128, 0);   // 100..115
    add(WOFF_CW4B, 64, 2, 64, 0);    // 116..123
    wt.nm = m;
  }

  k_detect<<<dim3(1), dim3(64), 0, stream>>>(d_in[3], FLAG);
  k_prep<<<dim3(40), dim3(256), 0, stream>>>(tab, W, FLAG);
  k_wbprep<<<dim3(NFRAG), dim3(64), 0, stream>>>(wt, W, WBu);
  k_pack<<<dim3(64), dim3(256), 0, stream>>>(d_in[0], d_in[1], d_in[2], d_in[5], PK, FLAG);
  k_knnp<<<dim3(NPTS / 256, BATCH, 2 * NPART), dim3(256), 0, stream>>>(PK, PART);
  k_merge<<<dim3(2 * BN / 256), dim3(256), 0, stream>>>(PK, PART, IDX);
  // transposes AFTER merge: PART aliases P1T/P2T
  k_tr<<<dim3(NPTS / 64, BATCH), dim3(64), 0, stream>>>(d_in[3], P1T, FLAG);
  k_tr<<<dim3(NPTS / 64, BATCH), dim3(64), 0, stream>>>(d_in[4], P2T, FLAG);
  k_logit<<<dim3(BN / 4, 2), dim3(256), 0, stream>>>(W, WBu, IDX, PK, AW);
  k_feat<<<dim3(BN / 4), dim3(256), 0, stream>>>(P1T, P2T, W, WBu, IDX, AW, PK, d_out, FLAG);
}

// Round 12
// 806.273 us; speedup vs baseline: 2.6206x; 1.0064x over previous
//
#include <hip/hip_runtime.h>
#include <hip/hip_bf16.h>
#include <math.h>

typedef __hip_bfloat16 bf16;

#define NPTS  8192
#define BATCH 2
#define KNB   16
#define NPART 16
#define PARTC (NPTS / NPART)   // 512
#define CAP   24               // knn pass-2 capture buffer per thread
#define BN    (BATCH * NPTS)

#define C_IE 0.9999950000374997f   // 1/sqrt(1+1e-5)
#define C_PM 0.9995003746877732f   // 1/sqrt(1+1e-3)

// v_perm_b32 byte selectors (SGPR-hoisted; bytes 0-3 pick from 2nd arg, 4-7 from 1st)
#define SEL_LO16 0x05040100u   // [b.b0, b.b1, a.b0, a.b1] == (b&0xffff)|(a<<16)
#define SEL_HI16 0x07060302u   // [b.b2, b.b3, a.b2, a.b3] == (b>>16)|(a&0xffff0000)

// ---- weight block float offsets inside ws ----
enum {
  WOFF_CW1A = 0,     WOFF_CB1A = 8192,  WOFF_CW1B = 8256,  WOFF_CB1B = 12352,
  WOFF_CW2A = 12416, WOFF_CB2A = 20608, WOFF_CW2B = 20672, WOFF_CB2B = 24768,
  WOFF_CW3A = 24832, WOFF_CB3A = 29120, WOFF_CW3B = 29184, WOFF_CB3B = 33280,
  WOFF_CW4A = 33344, WOFF_CB4A = 41536, WOFF_CW4B = 41600, WOFF_CB4B = 45696,
  WOFF_IEW1 = 45760, WOFF_IEB1 = 45952, WOFF_IEG  = 46016, WOFF_IEBT = 46080,
  WOFF_IEW2 = 46144, WOFF_IEB2 = 50240, WOFF_PECW = 50304, WOFF_PECB = 51840,
  WOFF_PMW1 = 51904, WOFF_PMB1 = 56000, WOFF_PMG1 = 56064, WOFF_PMT1 = 56128,
  WOFF_PMW2 = 56192, WOFF_PMB2 = 60288, WOFF_PMG2 = 60352, WOFF_PMT2 = 60416,
  WOFF_PMW3 = 60480, WOFF_PMB3 = 62528, WOFF_PMG3 = 62560, WOFF_PMT3 = 62592,
  WOFF_PMW4 = 62624, WOFF_PMB4 = 62656, WOFF_PMG4 = 62657, WOFF_PMT4 = 62658
};

// ---- ws byte offsets (PART u16 x NPART=16 = 16.8 MB from BOFF_PART ==
//      exactly the round-4 known-good extent of i32 x NPART=4) ----
#define BOFF_W    0u
#define BOFF_FLAG 262144u
#define BOFF_PK   262160u     // 4 x [B*N] float4 (1 MB)
#define BOFF_WB   1310736u    // MFMA weight frags: 124 x 64 lanes x 32 B = 248 KB
#define BOFF_IDX  2359312u    // final idx [2][B][N][16] i32 (2 MB)
#define BOFF_AW   4456464u    // attention weights u16 [2][B][N][16] (1 MB)
#define BOFF_P1T  5505040u    // points1^T packed hi|lo u32 [B][N][64] (4 MB)
#define BOFF_P2T  9699344u    // points2^T packed hi|lo u32 [B][N][64] (4 MB)
#define BOFF_PART BOFF_P1T    // knn partials aliased over P1T/P2T+slack; k_tr after k_merge

typedef __attribute__((ext_vector_type(4))) float f32x4;
typedef __attribute__((ext_vector_type(8))) short bf16x8;
typedef __attribute__((ext_vector_type(4))) unsigned int u32x4;

__device__ __forceinline__ float lrelu(float v) { return v > 0.f ? v : 0.1f * v; }

__device__ __forceinline__ float ldin(const void* p, size_t i, int f32) {
  return f32 ? ((const float*)p)[i] : __bfloat162float(((const bf16*)p)[i]);
}
__device__ __forceinline__ void stout(void* p, size_t i, float v, int f32) {
  if (f32) ((float*)p)[i] = v;
  else ((bf16*)p)[i] = __float2bfloat16(v);
}

// bf16 round-nearest-even split: x ~= hi + lo (hi,lo bf16 bit patterns)
__device__ __forceinline__ unsigned int bf16rne(float x) {
  unsigned int u = __float_as_uint(x);
  return (u + 0x7fffu + ((u >> 16) & 1u)) >> 16;
}
__device__ __forceinline__ void splitbf(float x, unsigned int& h, unsigned int& l) {
  h = bf16rne(x);
  float hf = __uint_as_float(h << 16);
  l = bf16rne(x - hf);
}
// (lo16(a) << 16) | lo16(b) in one v_perm_b32 (bit-identical to or/shl chain)
__device__ __forceinline__ unsigned int permpack(unsigned int a, unsigned int b) {
  return __builtin_amdgcn_perm(a, b, SEL_LO16);
}
__device__ __forceinline__ unsigned int packbf(float v) {
  unsigned int h, lo;
  splitbf(v, h, lo);
  return permpack(lo, h);   // h | (lo << 16)
}

// stable top-16 insertion (keeps lower index on ties when fed ascending j)
__device__ __forceinline__ void insert16(float d, int id, float* best, int* bidx) {
#pragma unroll
  for (int p = 0; p < KNB; ++p) {
    bool c = d < best[p];
    float tb = best[p]; int ti = bidx[p];
    best[p] = c ? d : tb; bidx[p] = c ? id : ti;
    d = c ? tb : d; id = c ? ti : id;
  }
}

// one bitonic compare-exchange pass over a 16-float register array.
// J,K are literal constants -> indices fold to constants, array stays in regs.
#define BPASS(arr, J, K) \
  _Pragma("unroll") \
  for (int i = 0; i < 16; ++i) { \
    int ix = i ^ (J); \
    if (ix > i) { \
      float lo = fminf(arr[i], arr[ix]); \
      float hi = fmaxf(arr[i], arr[ix]); \
      if ((i & (K)) == 0) { arr[i] = lo; arr[ix] = hi; } \
      else { arr[i] = hi; arr[ix] = lo; } \
    } \
  }

// exact reference distance chain (bit-replicates f32 expanded form)
__device__ __forceinline__ float qsq(float4 qv) {
  return __fadd_rn(__fadd_rn(__fmul_rn(qv.x, qv.x), __fmul_rn(qv.y, qv.y)),
                   __fmul_rn(qv.z, qv.z));
}
__device__ __forceinline__ float refdist(float4 qv, float sq, float4 rv) {
  float sr = qsq(rv);
  float dot = __fmaf_rn(qv.z, rv.z, __fmaf_rn(qv.y, rv.y, __fmul_rn(qv.x, rv.x)));
  return __fsub_rn(__fadd_rn(sq, sr), __fadd_rn(dot, dot));
}
__device__ __forceinline__ float refdist_sr(float4 qv, float sq, float4 rv) {
  float dot = __fmaf_rn(qv.z, rv.z, __fmaf_rn(qv.y, rv.y, __fmul_rn(qv.x, rv.x)));
  return __fsub_rn(__fadd_rn(sq, rv.w), __fadd_rn(dot, dot));
}

// ---------------- dtype autodetect ----------------
__global__ void k_detect(const void* __restrict__ pts1, int* __restrict__ flag) {
  int tid = threadIdx.x;  // 64
  const bf16* p = (const bf16*)pts1;
  int cnt = 0;
  for (int i = tid; i < 1024; i += 64) {
    float v = __bfloat162float(p[i]);
    if (!(fabsf(v) <= 64.f)) cnt++;
  }
#pragma unroll
  for (int s = 32; s; s >>= 1) cnt += __shfl_down(cnt, s);
  if (tid == 0) *flag = (cnt >= 8) ? 1 : 0;
}

// ---------------- prep ----------------
struct PrepTab {
  const void* src[40];
  int off[40];
  int n[40];
  float scale[40];
};

__global__ void k_prep(PrepTab tab, float* __restrict__ W, const int* __restrict__ flag) {
  int f32 = *flag;
  int a = blockIdx.x;
  const void* s = tab.src[a];
  float* d = W + tab.off[a];
  float sc = tab.scale[a];
  for (int i = threadIdx.x; i < tab.n[a]; i += blockDim.x) d[i] = ldin(s, i, f32) * sc;
}

// ---------------- MFMA weight fragment prep ----------------
// frag f: 64 lanes x {hi float4(8 bf16), lo float4}. B-layout: lane l holds
// W[srck(ks*32+(l>>4)*8+e)][nt*16+(l&15)], word r = elem2r | elem2r+1<<16.
// mode 0: srck = k (<kreal else 0). mode 1 (cw3a): A=[f2(64)|pd(3)|0]:
//   k<64 -> k+3; 64..66 -> k-64; else 0.
struct WTab { int woff[16]; int nn[16]; int kreal[16]; int mode[16]; int fb[16]; int nm; };

__global__ __launch_bounds__(64) void k_wbprep(WTab wt, const float* __restrict__ W,
                                               unsigned int* __restrict__ WB) {
  int f = blockIdx.x, l = threadIdx.x;
  int m = 0;
  for (int i = 1; i < wt.nm; ++i)
    if (wt.fb[i] <= f) m = i;
  int ntile = wt.nn[m] >> 4;
  int local = f - wt.fb[m];
  int ks = local / ntile, nt = local - ks * ntile;
  int g = l >> 4, c = l & 15;
  int col = nt * 16 + c;
  int N = wt.nn[m], kr = wt.kreal[m], wo = wt.woff[m], mode = wt.mode[m];
  unsigned int hw[4], lw[4];
#pragma unroll
  for (int r = 0; r < 4; ++r) {
    float wv2[2];
#pragma unroll
    for (int e = 0; e < 2; ++e) {
      int k = ks * 32 + g * 8 + 2 * r + e;
      int srck;
      if (mode == 1) srck = (k < 64) ? k + 3 : ((k < 67) ? k - 64 : -1);
      else srck = (k < kr) ? k : -1;
      wv2[e] = (srck >= 0) ? W[wo + srck * N + col] : 0.f;
    }
    unsigned int h0, l0, h1, l1;
    splitbf(wv2[0], h0, l0);
    splitbf(wv2[1], h1, l1);
    hw[r] = h0 | (h1 << 16);
    lw[r] = l0 | (l1 << 16);
  }
  unsigned int* d = WB + ((size_t)f * 64 + l) * 8;
  d[0] = hw[0]; d[1] = hw[1]; d[2] = hw[2]; d[3] = hw[3];
  d[4] = lw[0]; d[5] = lw[1]; d[6] = lw[2]; d[7] = lw[3];
}

// ---------------- pack (w = qsq, bit-identical chain to the old tile staging) --
__global__ void k_pack(const void* __restrict__ xyz1, const void* __restrict__ xyz2,
                       const void* __restrict__ xyz2w, const void* __restrict__ sf,
                       float4* __restrict__ pk, const int* __restrict__ flag) {
  int f32 = *flag;
  int t = blockIdx.x * 256 + threadIdx.x;  // B*N
  int b = t >> 13, n = t & (NPTS - 1);
  size_t base = (size_t)b * 3 * NPTS + n;
  float ax = ldin(xyz1, base, f32), ay = ldin(xyz1, base + NPTS, f32), az = ldin(xyz1, base + 2 * NPTS, f32);
  float sx = ldin(sf, base, f32),   sy = ldin(sf, base + NPTS, f32),   sz = ldin(sf, base + 2 * NPTS, f32);
  float4 p0 = make_float4(__fadd_rn(ax, sx), __fadd_rn(ay, sy), __fadd_rn(az, sz), 0.f);
  p0.w = qsq(p0);
  float4 p1 = make_float4(ax, ay, az, 0.f);
  p1.w = qsq(p1);
  float4 p2 = make_float4(ldin(xyz2, base, f32), ldin(xyz2, base + NPTS, f32), ldin(xyz2, base + 2 * NPTS, f32), 0.f);
  p2.w = qsq(p2);
  float4 p3 = make_float4(ldin(xyz2w, base, f32), ldin(xyz2w, base + NPTS, f32), ldin(xyz2w, base + 2 * NPTS, f32), 0.f);
  p3.w = qsq(p3);
  pk[t]          = p0;
  pk[t + BN]     = p1;
  pk[t + 2 * BN] = p2;
  pk[t + 3 * BN] = p3;
}

// ---------------- transpose (writes packed hi|lo u32) ----------------
__global__ __launch_bounds__(64) void k_tr(const void* __restrict__ src,
                                           unsigned int* __restrict__ dst,
                                           const int* __restrict__ flag) {
  __shared__ float tile[64][65];
  int f32 = *flag;
  int tid = threadIdx.x;
  int n0 = blockIdx.x * 64;
  int b = blockIdx.y;
  for (int i = 0; i < 64; ++i)
    tile[i][tid] = ldin(src, ((size_t)b * 64 + i) * NPTS + n0 + tid, f32);
  __syncthreads();
  for (int i = 0; i < 64; ++i)
    dst[((size_t)b * NPTS + n0 + i) * 64 + tid] = packbf(tile[tid][i]);
}

// ---------------- KNN partials: scalar-broadcast ref reads (no LDS tile) -----
// Ref addresses depend only on blockIdx + unrolled counters -> wave-uniform ->
// compiler emits s_load into SGPRs (SMEM pipe; frees the LDS 12cyc/b128 pipe).
// pk.w carries qsq (set in k_pack with the identical chain) -> refdist_sr
// values are bit-identical to the staged-tile version. Selection logic,
// capture order, and post are unchanged -> bit-identical indices.
__global__ __launch_bounds__(256) void k_knnp(const float4* __restrict__ pk,
                                              unsigned short* __restrict__ part_idx) {
  __shared__ unsigned short sbuf[256 * CAP];
  int tid = threadIdx.x;
  int n = blockIdx.x * 256 + tid;
  int b = blockIdx.y;
  int which = blockIdx.z >> 4;   // NPART==16
  int part  = blockIdx.z & 15;
  const float4* q = pk + (size_t)which * BN;
  const float4* r = pk + (size_t)(2 + which) * BN + (size_t)b * NPTS;
  float4 qv = q[b * NPTS + n];
  float sq = qsq(qv);

  float best[KNB];
#pragma unroll
  for (int p = 0; p < KNB; ++p) best[p] = 3.4e38f;   // sorted asc (all equal)

  const int c0 = part * PARTC;
  // pass 1: exact 16 smallest distance VALUES (batched bitonic)
  for (int t = 0; t < PARTC / 16; ++t) {
    const float4* rr = r + c0 + t * 16;   // uniform across the wave
    float fr[16];
#pragma unroll
    for (int j = 0; j < 16; ++j) fr[j] = refdist_sr(qv, sq, rr[j]);
    // bitonic sort fr ascending (10 passes)
    BPASS(fr, 1, 2)
    BPASS(fr, 2, 4) BPASS(fr, 1, 4)
    BPASS(fr, 4, 8) BPASS(fr, 2, 8) BPASS(fr, 1, 8)
    BPASS(fr, 8, 16) BPASS(fr, 4, 16) BPASS(fr, 2, 16) BPASS(fr, 1, 16)
    // min-merge: keep 16 smallest of best(asc) U fr(asc) -> bitonic in best
#pragma unroll
    for (int i = 0; i < 16; ++i) best[i] = fminf(best[i], fr[15 - i]);
    // bitonic cleanup -> best sorted asc again (K=16: all-ascending passes)
    BPASS(best, 8, 16) BPASS(best, 4, 16) BPASS(best, 2, 16) BPASS(best, 1, 16)
  }
  float thr = best[KNB - 1];

  // pass 2: capture candidate indices with dd <= thr (ascending global index)
  int cnt = 0;
  for (int t = 0; t < PARTC / 16; ++t) {
    const float4* rr = r + c0 + t * 16;   // uniform across the wave
#pragma unroll
    for (int j = 0; j < 16; ++j) {
      float dd = refdist_sr(qv, sq, rr[j]);
      if (dd <= thr && cnt < CAP) {
        sbuf[tid * CAP + cnt] = (unsigned short)(c0 + t * 16 + j);
        cnt++;
      }
    }
  }

  // post: exact (d, idx) selection among <=CAP captured
  float bd[KNB]; int bi[KNB];
#pragma unroll
  for (int p = 0; p < KNB; ++p) { bd[p] = 3.4e38f; bi[p] = 0; }
  for (int m = 0; m < CAP; ++m) {
    if (m < cnt) {
      int id = sbuf[tid * CAP + m];
      float dd = refdist(qv, sq, r[id]);
      insert16(dd, id, bd, bi);
    }
  }
  size_t o = ((((size_t)which * BATCH + b) * NPART + part) * NPTS + n) * KNB;
#pragma unroll
  for (int p = 0; p < KNB; ++p) part_idx[o + p] = (unsigned short)bi[p];
}

// ---------------- KNN merge (16 parts x 16 u16 candidates, ascending feed) ----
__global__ void k_merge(const float4* __restrict__ pk,
                        const unsigned short* __restrict__ part_idx,
                        int* __restrict__ idxf) {
  int t = blockIdx.x * 256 + threadIdx.x;  // (which*B+b)*N+n
  int n = t & (NPTS - 1);
  int wb = t >> 13;
  int b = wb & (BATCH - 1);
  int which = wb / BATCH;
  const float4* q = pk + (size_t)which * BN;
  const float4* r = pk + (size_t)(2 + which) * BN + (size_t)b * NPTS;
  float4 qv = q[b * NPTS + n];
  float sq = qsq(qv);
  float best[KNB]; int bidx[KNB];
#pragma unroll
  for (int p = 0; p < KNB; ++p) { best[p] = 3.4e38f; bidx[p] = 0; }
  for (int part = 0; part < NPART; ++part) {
    size_t o = ((((size_t)which * BATCH + b) * NPART + part) * NPTS + n) * KNB;
#pragma unroll
    for (int m = 0; m < KNB; ++m) {
      int id = part_idx[o + m];
      float dd = refdist(qv, sq, r[id]);
      if (dd < best[KNB - 1]) insert16(dd, id, best, bidx);
    }
  }
  size_t oo = (size_t)t * KNB;
#pragma unroll
  for (int p = 0; p < KNB; ++p) idxf[oo + p] = bidx[p];
}

// ---------------- MFMA helpers ----------------
__device__ __forceinline__ bf16x8 mk8(unsigned int w0, unsigned int w1,
                                      unsigned int w2, unsigned int w3) {
  u32x4 u;
  u.x = w0; u.y = w1; u.z = w2; u.w = w3;
  return __builtin_bit_cast(bf16x8, u);
}

// build A hi/lo frags from 8 packed (hi|lo<<16) u32 via v_perm_b32 byte-selects
// (1 op/word vs 3 for and/shift/or; bit-identical)
__device__ __forceinline__ void mkA_pk(u32x4 qa, u32x4 qb, bf16x8& ah, bf16x8& al) {
  ah = mk8(__builtin_amdgcn_perm(qa.y, qa.x, SEL_LO16),
           __builtin_amdgcn_perm(qa.w, qa.z, SEL_LO16),
           __builtin_amdgcn_perm(qb.y, qb.x, SEL_LO16),
           __builtin_amdgcn_perm(qb.w, qb.z, SEL_LO16));
  al = mk8(__builtin_amdgcn_perm(qa.y, qa.x, SEL_HI16),
           __builtin_amdgcn_perm(qa.w, qa.z, SEL_HI16),
           __builtin_amdgcn_perm(qb.y, qb.x, SEL_HI16),
           __builtin_amdgcn_perm(qb.w, qb.z, SEL_HI16));
}
__device__ __forceinline__ void mkA_lds(const unsigned int* p, bf16x8& ah, bf16x8& al) {
  mkA_pk(*(const u32x4*)p, *(const u32x4*)(p + 4), ah, al);
}

#define FRAG_IEW2 0
#define FRAG_PECW 8
#define FRAG_PMW1 12
#define FRAG_PMW2 20
#define FRAG_PMW3 28
#define FRAG_C1A  32
#define FRAG_C1B  48
#define FRAG_C2A  56
#define FRAG_C2B  72
#define FRAG_C3A  80
#define FRAG_C3B  92
#define FRAG_C4A  100
#define FRAG_C4B  116
#define NFRAG     124

// acc += A * Wfrag with split-bf16 3-product emulation
__device__ __forceinline__ f32x4 mfma_bb(bf16x8 ah, bf16x8 al,
                                         const unsigned int* __restrict__ WB,
                                         int f, int lane, f32x4 acc) {
  const u32x4* p = (const u32x4*)WB + ((size_t)(f * 64 + lane)) * 2;
  u32x4 h4 = p[0], l4 = p[1];
  bf16x8 bh = __builtin_bit_cast(bf16x8, h4);
  bf16x8 bl = __builtin_bit_cast(bf16x8, l4);
  acc = __builtin_amdgcn_mfma_f32_16x16x32_bf16(al, bh, acc, 0, 0, 0);
  acc = __builtin_amdgcn_mfma_f32_16x16x32_bf16(ah, bl, acc, 0, 0, 0);
  acc = __builtin_amdgcn_mfma_f32_16x16x32_bf16(ah, bh, acc, 0, 0, 0);
  return acc;
}

// one 64->64 layer: A from xp (sample row = lane&15), 2 k-steps x 4 n-tiles
__device__ __forceinline__ void layer64(const unsigned int* __restrict__ xp,
                                        const unsigned int* __restrict__ WB,
                                        int fbase, int lane, f32x4 acc[4]) {
  int c = lane & 15, g = lane >> 4;
  bf16x8 ah0, al0, ah1, al1;
  mkA_lds(xp + c * 68 + g * 8, ah0, al0);
  mkA_lds(xp + c * 68 + 32 + g * 8, ah1, al1);
#pragma unroll
  for (int nt = 0; nt < 4; ++nt) {
    acc[nt] = mfma_bb(ah0, al0, WB, fbase + nt, lane, acc[nt]);
    acc[nt] = mfma_bb(ah1, al1, WB, fbase + 4 + nt, lane, acc[nt]);
  }
}

// epilogue: optional bn(+relu), split to bf16 hi/lo, pack, write to xp
__device__ __forceinline__ void epi_pack(int lane, f32x4 acc[4], unsigned int* xp,
                                         const float* gw, const float* bw, bool relu) {
  int c = lane & 15, g = lane >> 4;
#pragma unroll
  for (int nt = 0; nt < 4; ++nt) {
    float gv = gw ? gw[nt * 16 + c] : 1.f;
    float bv = gw ? bw[nt * 16 + c] : 0.f;
#pragma unroll
    for (int r = 0; r < 4; ++r) {
      float v = acc[nt][r];
      if (gw) v = fmaf(v, gv, bv);
      if (relu) v = fmaxf(v, 0.f);
      xp[(g * 4 + r) * 68 + nt * 16 + c] = packbf(v);
    }
  }
}

// epilogue with leaky relu (k_feat chains)
__device__ __forceinline__ void epi_lrelu(int lane, f32x4 acc[4], unsigned int* xp) {
  int c = lane & 15, g = lane >> 4;
#pragma unroll
  for (int nt = 0; nt < 4; ++nt) {
#pragma unroll
    for (int r = 0; r < 4; ++r)
      xp[(g * 4 + r) * 68 + nt * 16 + c] = packbf(lrelu(acc[nt][r]));
  }
}

// ---------------- k_logit: IPC MLP on matrix cores (split-bf16), softmax ------
__global__ __launch_bounds__(256, 3) void k_logit(const float* __restrict__ W,
                                                  const unsigned int* __restrict__ WB,
                                                  const int* __restrict__ idxf,
                                                  const float4* __restrict__ pk,
                                                  unsigned short* __restrict__ AW) {
  __shared__ unsigned int xp_s[4][16 * 68];  // packed hi|lo activations per sample
  __shared__ unsigned int tg_s[4][16 * 36];  // packed trig rows (24 real + 8 zero)
  const int l = threadIdx.x & 63;
  const int wv = threadIdx.x >> 6;
  const int c = l & 15, g = l >> 4;
  unsigned int* xp = xp_s[wv];
  unsigned int* tg = tg_s[wv];
  const int which = blockIdx.y;
  const int pt = blockIdx.x * 4 + wv;    // b*N+n
  const int n = pt & (NPTS - 1);
  const int b = pt >> 13;

  int idxv = idxf[(((size_t)which * BATCH + b) * NPTS + n) * KNB + c];
  float4 pv = pk[(size_t)2 * BN + (size_t)b * NPTS + idxv];  // x2[idx]
  float4 qp = pk[(size_t)BN + pt];                           // x1[n]
  float pdx = pv.x - qp.x, pdy = pv.y - qp.y, pdz = pv.z - qp.z;

  // ---- trig: 12 sincos per sample, 3 per k-group lane ----
  {
    unsigned int* tr = tg + c * 36;
#pragma unroll
    for (int j = 0; j < 3; ++j) {
      int t = g * 3 + j;
      int c3 = t >> 2, fq = t & 3;
      float pdc = (c3 == 0) ? pdx : (c3 == 1) ? pdy : pdz;
      float pe = (pdc - rintf(pdc * 4.f) * 0.25f) * 4.f;
      float tt = pe / 1.000001f * 6.28318530717958647692f;
      float dv = (fq == 0) ? 1.f : (fq == 1) ? 10.f : (fq == 2) ? 100.f : 1000.f;
      float sn, cs;
      sincosf(tt / dv, &sn, &cs);
      unsigned int hs, ls2, hc, lc;
      splitbf(sn, hs, ls2);
      splitbf(cs, hc, lc);
      tr[2 * t] = permpack(ls2, hs);
      tr[2 * t + 1] = permpack(lc, hc);
    }
    if (g == 3) {
#pragma unroll
      for (int z = 24; z < 32; ++z) tr[z] = 0u;
    }
  }

  // ---- ie1: 3->64, bn, relu (exact f32), pack to xp[sample=c][ch] ----
  {
    unsigned int* xr = xp + c * 68 + g * 16;
#pragma unroll
    for (int m4 = 0; m4 < 4; ++m4) {
      int ch = g * 16 + m4 * 4;
      float4 bb = *(const float4*)(W + WOFF_IEB1 + ch);
      float4 w0 = *(const float4*)(W + WOFF_IEW1 + ch);
      float4 w1 = *(const float4*)(W + WOFF_IEW1 + 64 + ch);
      float4 w2 = *(const float4*)(W + WOFF_IEW1 + 128 + ch);
      float4 gg = *(const float4*)(W + WOFF_IEG + ch);
      float4 bt = *(const float4*)(W + WOFF_IEBT + ch);
      float v0 = fmaf(pdz, w2.x, fmaf(pdy, w1.x, fmaf(pdx, w0.x, bb.x)));
      float v1 = fmaf(pdz, w2.y, fmaf(pdy, w1.y, fmaf(pdx, w0.y, bb.y)));
      float v2 = fmaf(pdz, w2.z, fmaf(pdy, w1.z, fmaf(pdx, w0.z, bb.z)));
      float v3 = fmaf(pdz, w2.w, fmaf(pdy, w1.w, fmaf(pdx, w0.w, bb.w)));
      v0 = fmaxf(fmaf(v0, gg.x, bt.x), 0.f);
      v1 = fmaxf(fmaf(v1, gg.y, bt.y), 0.f);
      v2 = fmaxf(fmaf(v2, gg.z, bt.z), 0.f);
      v3 = fmaxf(fmaf(v3, gg.w, bt.w), 0.f);
      u32x4 pk4;
      pk4.x = packbf(v0); pk4.y = packbf(v1);
      pk4.z = packbf(v2); pk4.w = packbf(v3);
      *(u32x4*)(xr + m4 * 4) = pk4;
    }
  }
  __builtin_amdgcn_wave_barrier();

  f32x4 acc[4];
  // ---- ie2 + pec (accumulated into one f32 acc; init = ie_b2 + pec_b) ----
#pragma unroll
  for (int nt = 0; nt < 4; ++nt) {
    float bs = W[WOFF_IEB2 + nt * 16 + c] + W[WOFF_PECB + nt * 16 + c];
    acc[nt].x = bs; acc[nt].y = bs; acc[nt].z = bs; acc[nt].w = bs;
  }
  layer64(xp, WB, FRAG_IEW2, l, acc);
  {
    bf16x8 ah, al;
    mkA_lds(tg + c * 36 + g * 8, ah, al);
#pragma unroll
    for (int nt = 0; nt < 4; ++nt)
      acc[nt] = mfma_bb(ah, al, WB, FRAG_PECW + nt, l, acc[nt]);
  }
  __builtin_amdgcn_wave_barrier();
  epi_pack(l, acc, xp, nullptr, nullptr, false);
  __builtin_amdgcn_wave_barrier();

  // ---- pm1: 64->64, bn, relu ----
#pragma unroll
  for (int nt = 0; nt < 4; ++nt) {
    float bs = W[WOFF_PMB1 + nt * 16 + c];
    acc[nt].x = bs; acc[nt].y = bs; acc[nt].z = bs; acc[nt].w = bs;
  }
  layer64(xp, WB, FRAG_PMW1, l, acc);
  __builtin_amdgcn_wave_barrier();
  epi_pack(l, acc, xp, W + WOFF_PMG1, W + WOFF_PMT1, true);
  __builtin_amdgcn_wave_barrier();

  // ---- pm2: 64->64, bn, relu ----
#pragma unroll
  for (int nt = 0; nt < 4; ++nt) {
    float bs = W[WOFF_PMB2 + nt * 16 + c];
    acc[nt].x = bs; acc[nt].y = bs; acc[nt].z = bs; acc[nt].w = bs;
  }
  layer64(xp, WB, FRAG_PMW2, l, acc);
  __builtin_amdgcn_wave_barrier();
  epi_pack(l, acc, xp, W + WOFF_PMG2, W + WOFF_PMT2, true);
  __builtin_amdgcn_wave_barrier();

  // ---- pm3: 64->32, bn (no relu), stays in regs ----
  f32x4 a3[2];
#pragma unroll
  for (int nt = 0; nt < 2; ++nt) {
    float bs = W[WOFF_PMB3 + nt * 16 + c];
    a3[nt].x = bs; a3[nt].y = bs; a3[nt].z = bs; a3[nt].w = bs;
  }
  {
    bf16x8 ah0, al0, ah1, al1;
    mkA_lds(xp + c * 68 + g * 8, ah0, al0);
    mkA_lds(xp + c * 68 + 32 + g * 8, ah1, al1);
#pragma unroll
    for (int nt = 0; nt < 2; ++nt) {
      a3[nt] = mfma_bb(ah0, al0, WB, FRAG_PMW3 + nt, l, a3[nt]);
      a3[nt] = mfma_bb(ah1, al1, WB, FRAG_PMW3 + 2 + nt, l, a3[nt]);
    }
  }
#pragma unroll
  for (int nt = 0; nt < 2; ++nt) {
    float gv = W[WOFF_PMG3 + nt * 16 + c];
    float bv = W[WOFF_PMT3 + nt * 16 + c];
#pragma unroll
    for (int r = 0; r < 4; ++r) a3[nt][r] = fmaf(a3[nt][r], gv, bv);
  }

  // ---- pm4 dot (per-lane 2-ch partial, 16-lane butterfly) + bn ----
  float w4a = W[WOFF_PMW4 + c];
  float w4b = W[WOFF_PMW4 + 16 + c];
  f32x4 pr;
#pragma unroll
  for (int r = 0; r < 4; ++r) pr[r] = fmaf(a3[1][r], w4b, a3[0][r] * w4a);
#pragma unroll
  for (int s = 1; s < 16; s <<= 1) {
#pragma unroll
    for (int r = 0; r < 4; ++r) pr[r] += __shfl_xor(pr[r], s);
  }
  float b4 = W[WOFF_PMB4], g4 = W[WOFF_PMG4], t4 = W[WOFF_PMT4];
  f32x4 lg;
#pragma unroll
  for (int r = 0; r < 4; ++r) lg[r] = fmaf(pr[r] + b4, g4, t4);

  // ---- softmax over 16 neighbors (samples): group g holds samples 4g+r ----
  float m = fmaxf(fmaxf(lg[0], lg[1]), fmaxf(lg[2], lg[3]));
#pragma unroll
  for (int s = 16; s < 64; s <<= 1) m = fmaxf(m, __shfl_xor(m, s));
  f32x4 e;
  float ssum = 0.f;
#pragma unroll
  for (int r = 0; r < 4; ++r) { e[r] = expf(lg[r] - m); ssum += e[r]; }
#pragma unroll
  for (int s = 16; s < 64; s <<= 1) ssum += __shfl_xor(ssum, s);
  if (c < 4) {
    int k = g * 4 + c;
    float ev = (c == 0) ? e[0] : (c == 1) ? e[1] : (c == 2) ? e[2] : e[3];
    float aw = ev / ssum;
    AW[(((size_t)which * BATCH + b) * NPTS + n) * KNB + k] =
        (unsigned short)__float2uint_rn(aw * 65535.f);
  }
}

// ---------------- k_feat: chains on matrix cores (split-bf16) ----------------
// block = 4 waves = 4 points; wave = one point's 16 neighbors (16-sample batch).
__global__ __launch_bounds__(256, 3) void k_feat(const unsigned int* __restrict__ P1T,
                                                 const unsigned int* __restrict__ P2T,
                                                 const float* __restrict__ W,
                                                 const unsigned int* __restrict__ WB,
                                                 const int* __restrict__ idxf,
                                                 const unsigned short* __restrict__ AW,
                                                 const float4* __restrict__ pk,
                                                 void* __restrict__ out,
                                                 const int* __restrict__ flag) {
  __shared__ unsigned int xp_s[4][16 * 68];
  __shared__ unsigned int costb[4][132];   // [point][costA(64)|costB(64)] packed
  __shared__ unsigned int u4b[4][68];      // chain4 mid activations [point][64]
  __shared__ float awb[4][16];
  const int l = threadIdx.x & 63;
  const int wv = threadIdx.x >> 6;
  const int c = l & 15, g = l >> 4;
  unsigned int* xp = xp_s[wv];
  const int f32 = *flag;
  const int pt = blockIdx.x * 4 + wv;    // b*N+n
  const int n = pt & (NPTS - 1);
  const int b = pt >> 13;
  float4 qp = pk[(size_t)BN + pt];       // x1[n]
  u32x4 z4;
  z4.x = 0u; z4.y = 0u; z4.z = 0u; z4.w = 0u;

  // gp1 fragments (layer-a k-steps 0,1): row n broadcast
  bf16x8 p1h[2], p1l[2];
  {
    const unsigned int* pr = P1T + ((size_t)b * NPTS + n) * 64;
#pragma unroll
    for (int ks = 0; ks < 2; ++ks) {
      u32x4 qa = *(const u32x4*)(pr + ks * 32 + g * 8);
      u32x4 qb = *(const u32x4*)(pr + ks * 32 + g * 8 + 4);
      mkA_pk(qa, qb, p1h[ks], p1l[ks]);
    }
  }

  for (int which = 0; which < 2; ++which) {
    int idxv = idxf[(((size_t)which * BATCH + b) * NPTS + n) * KNB + c];
    float4 pv = pk[(size_t)2 * BN + (size_t)b * NPTS + idxv];  // x2[idx]
    float pdx = pv.x - qp.x, pdy = pv.y - qp.y, pdz = pv.z - qp.z;
    float aw = (float)AW[(((size_t)which * BATCH + b) * NPTS + n) * KNB + c] *
               (1.f / 65535.f);
    if (g == 0) awb[wv][c] = aw;

    // gp2 fragments (layer-a k-steps 2,3): per-sample row idxv
    bf16x8 p2h[2], p2l[2];
    {
      const unsigned int* qr = P2T + ((size_t)b * NPTS + idxv) * 64;
#pragma unroll
      for (int ks = 0; ks < 2; ++ks) {
        u32x4 qa = *(const u32x4*)(qr + ks * 32 + g * 8);
        u32x4 qb = *(const u32x4*)(qr + ks * 32 + g * 8 + 4);
        mkA_pk(qa, qb, p2h[ks], p2l[ks]);
      }
    }

    // ---- layer a: [gp1|gp2](128) -> 64 ----
    f32x4 acc[4];
    {
      const float* Ba = W + (which == 0 ? WOFF_CB1A : WOFF_CB2A);
      int fa = (which == 0) ? FRAG_C1A : FRAG_C2A;
#pragma unroll
      for (int nt = 0; nt < 4; ++nt) {
        float bs = Ba[nt * 16 + c];
        acc[nt].x = bs; acc[nt].y = bs; acc[nt].z = bs; acc[nt].w = bs;
      }
#pragma unroll
      for (int nt = 0; nt < 4; ++nt) {
        acc[nt] = mfma_bb(p1h[0], p1l[0], WB, fa + nt, l, acc[nt]);
        acc[nt] = mfma_bb(p1h[1], p1l[1], WB, fa + 4 + nt, l, acc[nt]);
        acc[nt] = mfma_bb(p2h[0], p2l[0], WB, fa + 8 + nt, l, acc[nt]);
        acc[nt] = mfma_bb(p2h[1], p2l[1], WB, fa + 12 + nt, l, acc[nt]);
      }
    }
    __builtin_amdgcn_wave_barrier();
    epi_lrelu(l, acc, xp);
    __builtin_amdgcn_wave_barrier();

    // ---- layer b: 64 -> 64 ----
    {
      const float* Bb = W + (which == 0 ? WOFF_CB1B : WOFF_CB2B);
      int fb = (which == 0) ? FRAG_C1B : FRAG_C2B;
      bf16x8 ah0, al0, ah1, al1;
      mkA_lds(xp + c * 68 + g * 8, ah0, al0);
      mkA_lds(xp + c * 68 + 32 + g * 8, ah1, al1);
#pragma unroll
      for (int nt = 0; nt < 4; ++nt) {
        float bs = Bb[nt * 16 + c];
        acc[nt].x = bs; acc[nt].y = bs; acc[nt].z = bs; acc[nt].w = bs;
        acc[nt] = mfma_bb(ah0, al0, WB, fb + nt, l, acc[nt]);
        acc[nt] = mfma_bb(ah1, al1, WB, fb + 4 + nt, l, acc[nt]);
      }
    }
    __builtin_amdgcn_wave_barrier();

    if (which == 1) {
      // ---- cw3a: A = [lrelu(f2)(cols 0..63) | pd(64..66) | 0] (weights permuted) ----
      epi_lrelu(l, acc, xp);
      if (g == 0) {
        xp[c * 68 + 64] = packbf(pdx);
        xp[c * 68 + 65] = packbf(pdy);
        xp[c * 68 + 66] = packbf(pdz);
        xp[c * 68 + 67] = 0u;
      }
      __builtin_amdgcn_wave_barrier();
      {
        bf16x8 ah0, al0, ah1, al1, ah2, al2;
        mkA_lds(xp + c * 68 + g * 8, ah0, al0);
        mkA_lds(xp + c * 68 + 32 + g * 8, ah1, al1);
        u32x4 qa3 = z4;
        if (g == 0) qa3 = *(const u32x4*)(xp + c * 68 + 64);
        mkA_pk(qa3, z4, ah2, al2);
#pragma unroll
        for (int nt = 0; nt < 4; ++nt) {
          float bs = W[WOFF_CB3A + nt * 16 + c];
          acc[nt].x = bs; acc[nt].y = bs; acc[nt].z = bs; acc[nt].w = bs;
          acc[nt] = mfma_bb(ah0, al0, WB, FRAG_C3A + nt, l, acc[nt]);
          acc[nt] = mfma_bb(ah1, al1, WB, FRAG_C3A + 4 + nt, l, acc[nt]);
          acc[nt] = mfma_bb(ah2, al2, WB, FRAG_C3A + 8 + nt, l, acc[nt]);
        }
      }
      __builtin_amdgcn_wave_barrier();
      epi_lrelu(l, acc, xp);
      __builtin_amdgcn_wave_barrier();
      // ---- cw3b: 64 -> 64 ----
      {
        bf16x8 ah0, al0, ah1, al1;
        mkA_lds(xp + c * 68 + g * 8, ah0, al0);
        mkA_lds(xp + c * 68 + 32 + g * 8, ah1, al1);
#pragma unroll
        for (int nt = 0; nt < 4; ++nt) {
          float bs = W[WOFF_CB3B + nt * 16 + c];
          acc[nt].x = bs; acc[nt].y = bs; acc[nt].z = bs; acc[nt].w = bs;
          acc[nt] = mfma_bb(ah0, al0, WB, FRAG_C3B + nt, l, acc[nt]);
          acc[nt] = mfma_bb(ah1, al1, WB, FRAG_C3B + 4 + nt, l, acc[nt]);
        }
      }
      __builtin_amdgcn_wave_barrier();
    }

    // ---- weighted sum over 16 neighbors -> cost row, stage to costb ----
    {
      float4 a4r = *(const float4*)&awb[wv][g * 4];
#pragma unroll
      for (int nt = 0; nt < 4; ++nt) {
        float s = lrelu(acc[nt][0]) * a4r.x;
        s = fmaf(lrelu(acc[nt][1]), a4r.y, s);
        s = fmaf(lrelu(acc[nt][2]), a4r.z, s);
        s = fmaf(lrelu(acc[nt][3]), a4r.w, s);
        s += __shfl_xor(s, 16);
        s += __shfl_xor(s, 32);
        if (g == 0) costb[wv][which * 64 + nt * 16 + c] = packbf(s);
      }
    }
  }
  __syncthreads();

  // ---- chain4 layer a: batch-4 points (A rows 0..3), n-tile = wv ----
  f32x4 a4;
  {
    float bs = W[WOFF_CB4A + wv * 16 + c];
    a4.x = bs; a4.y = bs; a4.z = bs; a4.w = bs;
#pragma unroll
    for (int ks = 0; ks < 4; ++ks) {
      u32x4 qa = z4, qb = z4;
      if (c < 4) {
        qa = *(const u32x4*)(&costb[c][ks * 32 + g * 8]);
        qb = *(const u32x4*)(&costb[c][ks * 32 + g * 8 + 4]);
      }
      bf16x8 ah, al;
      mkA_pk(qa, qb, ah, al);
      a4 = mfma_bb(ah, al, WB, FRAG_C4A + ks * 4 + wv, l, a4);
    }
  }
  if (g == 0) {
#pragma unroll
    for (int r = 0; r < 4; ++r) u4b[r][wv * 16 + c] = packbf(lrelu(a4[r]));
  }
  __syncthreads();

  // ---- chain4 layer b + output ----
  {
    float bs = W[WOFF_CB4B + wv * 16 + c];
    a4.x = bs; a4.y = bs; a4.z = bs; a4.w = bs;
#pragma unroll
    for (int ks = 0; ks < 2; ++ks) {
      u32x4 qa = z4, qb = z4;
      if (c < 4) {
        qa = *(const u32x4*)(&u4b[c][ks * 32 + g * 8]);
        qb = *(const u32x4*)(&u4b[c][ks * 32 + g * 8 + 4]);
      }
      bf16x8 ah, al;
      mkA_pk(qa, qb, ah, al);
      a4 = mfma_bb(ah, al, WB, FRAG_C4B + ks * 4 + wv, l, a4);
    }
  }
  if (g == 0) {
    int n0 = (blockIdx.x * 4) & (NPTS - 1);
    int b0 = (blockIdx.x * 4) >> 13;
    size_t ob = (size_t)b0 * 64 * NPTS + (size_t)(wv * 16 + c) * NPTS + n0;
#pragma unroll
    for (int r = 0; r < 4; ++r) stout(out, ob + r, lrelu(a4[r]), f32);
  }
}

// ---------------- host ----------------
extern "C" void kernel_launch(void* const* d_in, const int* in_sizes, int n_in,
                              void* d_out, int out_size, void* d_ws, size_t ws_size,
                              hipStream_t stream) {
  (void)in_sizes; (void)n_in; (void)out_size; (void)ws_size;
  float*  W    = (float*)d_ws;
  int*    FLAG = (int*)((char*)d_ws + BOFF_FLAG);
  float4* PK   = (float4*)((char*)d_ws + BOFF_PK);
  unsigned int* WBu = (unsigned int*)((char*)d_ws + BOFF_WB);
  int*    IDX  = (int*)((char*)d_ws + BOFF_IDX);
  unsigned short* AW = (unsigned short*)((char*)d_ws + BOFF_AW);
  unsigned int* P1T = (unsigned int*)((char*)d_ws + BOFF_P1T);
  unsigned int* P2T = (unsigned int*)((char*)d_ws + BOFF_P2T);
  unsigned short* PART = (unsigned short*)((char*)d_ws + BOFF_PART);

  static const int WOFFS[40] = {
    WOFF_CW1A, WOFF_CB1A, WOFF_CW1B, WOFF_CB1B,
    WOFF_CW2A, WOFF_CB2A, WOFF_CW2B, WOFF_CB2B,
    WOFF_CW3A, WOFF_CB3A, WOFF_CW3B, WOFF_CB3B,
    WOFF_CW4A, WOFF_CB4A, WOFF_CW4B, WOFF_CB4B,
    WOFF_IEW1, WOFF_IEB1, WOFF_IEG,  WOFF_IEBT,
    WOFF_IEW2, WOFF_IEB2, WOFF_PECW, WOFF_PECB,
    WOFF_PMW1, WOFF_PMB1, WOFF_PMG1, WOFF_PMT1,
    WOFF_PMW2, WOFF_PMB2, WOFF_PMG2, WOFF_PMT2,
    WOFF_PMW3, WOFF_PMB3, WOFF_PMG3, WOFF_PMT3,
    WOFF_PMW4, WOFF_PMB4, WOFF_PMG4, WOFF_PMT4};
  static const int WNS[40] = {
    8192, 64, 4096, 64,  8192, 64, 4096, 64,  4288, 64, 4096, 64,
    8192, 64, 4096, 64,  192, 64, 64, 64,  4096, 64,  1536, 64,
    4096, 64, 64, 64,  4096, 64, 64, 64,  2048, 32, 32, 32,  32, 1, 1, 1};

  PrepTab tab;
  for (int a = 0; a < 40; ++a) {
    tab.src[a] = d_in[6 + a];
    tab.off[a] = WOFFS[a];
    tab.n[a] = WNS[a];
    tab.scale[a] = 1.f;
  }
  tab.scale[18] = C_IE;                               // ie_g
  tab.scale[26] = C_PM; tab.scale[30] = C_PM;         // pm_g1, pm_g2
  tab.scale[34] = C_PM; tab.scale[38] = C_PM;         // pm_g3, pm_g4

  // fragment table: frag f = fb[m] + ks*(N/16) + nt
  WTab wt;
  {
    int f = 0, m = 0;
    auto add = [&](int woff, int N, int nks, int kreal, int mode) {
      wt.woff[m] = woff; wt.nn[m] = N; wt.kreal[m] = kreal;
      wt.mode[m] = mode; wt.fb[m] = f;
      f += nks * (N / 16); ++m;
    };
    add(WOFF_IEW2, 64, 2, 64, 0);    // 0..7
    add(WOFF_PECW, 64, 1, 24, 0);    // 8..11
    add(WOFF_PMW1, 64, 2, 64, 0);    // 12..19
    add(WOFF_PMW2, 64, 2, 64, 0);    // 20..27
    add(WOFF_PMW3, 32, 2, 64, 0);    // 28..31
    add(WOFF_CW1A, 64, 4, 128, 0);   // 32..47
    add(WOFF_CW1B, 64, 2, 64, 0);    // 48..55
    add(WOFF_CW2A, 64, 4, 128, 0);   // 56..71
    add(WOFF_CW2B, 64, 2, 64, 0);    // 72..79
    add(WOFF_CW3A, 64, 3, 67, 1);    // 80..91 (row-permuted [f2|pd|0])
    add(WOFF_CW3B, 64, 2, 64, 0);    // 92..99
    add(WOFF_CW4A, 64, 4, 128, 0);   // 100..115
    add(WOFF_CW4B, 64, 2, 64, 0);    // 116..123
    wt.nm = m;
  }

  k_detect<<<dim3(1), dim3(64), 0, stream>>>(d_in[3], FLAG);
  k_prep<<<dim3(40), dim3(256), 0, stream>>>(tab, W, FLAG);
  k_wbprep<<<dim3(NFRAG), dim3(64), 0, stream>>>(wt, W, WBu);
  k_pack<<<dim3(64), dim3(256), 0, stream>>>(d_in[0], d_in[1], d_in[2], d_in[5], PK, FLAG);
  k_knnp<<<dim3(NPTS / 256, BATCH, 2 * NPART), dim3(256), 0, stream>>>(PK, PART);
  k_merge<<<dim3(2 * BN / 256), dim3(256), 0, stream>>>(PK, PART, IDX);
  // transposes AFTER merge: PART aliases P1T/P2T
  k_tr<<<dim3(NPTS / 64, BATCH), dim3(64), 0, stream>>>(d_in[3], P1T, FLAG);
  k_tr<<<dim3(NPTS / 64, BATCH), dim3(64), 0, stream>>>(d_in[4], P2T, FLAG);
  k_logit<<<dim3(BN / 4, 2), dim3(256), 0, stream>>>(W, WBu, IDX, PK, AW);
  k_feat<<<dim3(BN / 4), dim3(256), 0, stream>>>(P1T, P2T, W, WBu, IDX, AW, PK, d_out, FLAG);
}